// Round 2
// baseline (1040.084 us; speedup 1.0000x reference)
//
#include <hip/hip_runtime.h>
#include <stdint.h>

#define NROWS 500000
#define NROWS4 125000
#define NCLS 100
#define NBINS 15
#define NSUB 64          // sub-bucket = 4096 ULP; ~70 elems/sub near mode -> rank err << tolerance
#define B1 14
#define CH1 8929         // ceil(125000/14) float4s per hist1 block
#define B2 16
#define CH2 7813         // ceil(125000/16) float4s per scan2 block
#define HSZ (NBINS * NSUB)   // 960

__device__ __forceinline__ int rank_target(int b) {
    if (b == 0) return 0;
    const float step = 500000.0f / 15.0f;   // float32-rounded, mimics jnp.linspace
    return (int)floorf((float)b * step);
}

// Pass 1: row softmax of logits [N][C], write transposed probsT [C][N].
// Also emits labConf[n] = prob of the labeled class (bit-identical product to
// the stored probsT value), so k_label never has to gather probsT.
__global__ __launch_bounds__(256) void k_softmax_t(const float* __restrict__ logits,
                                                   const int* __restrict__ labels,
                                                   float* __restrict__ probsT,
                                                   float* __restrict__ labConf) {
    __shared__ float tile[64][101];
    __shared__ float red[256];
    __shared__ float mx[64];
    __shared__ float inv[64];
    const int row0 = blockIdx.x * 64;
    const int rows = min(64, NROWS - row0);
    const int t = threadIdx.x;
    const int total = rows * NCLS;
    for (int k = t; k < total; k += 256) {
        int r = k / NCLS, c = k - r * NCLS;
        tile[r][c] = logits[(size_t)(row0 + r) * NCLS + c];
    }
    __syncthreads();
    const int r = t >> 2, q = t & 3;   // 4 threads per row
    if (r < rows) {
        float m = -1e30f;
        #pragma unroll
        for (int c = 0; c < 25; ++c) m = fmaxf(m, tile[r][q * 25 + c]);
        red[t] = m;
    }
    __syncthreads();
    if (r < rows && q == 0)
        mx[r] = fmaxf(fmaxf(red[t], red[t + 1]), fmaxf(red[t + 2], red[t + 3]));
    __syncthreads();
    if (r < rows) {
        float m = mx[r], s = 0.f;
        #pragma unroll
        for (int c = 0; c < 25; ++c) {
            float e = __expf(tile[r][q * 25 + c] - m);
            tile[r][q * 25 + c] = e;
            s += e;
        }
        red[t] = s;
    }
    __syncthreads();
    if (r < rows && q == 0)
        inv[r] = 1.0f / (red[t] + red[t + 1] + red[t + 2] + red[t + 3]);
    __syncthreads();
    if (t < rows) {
        const int lab = labels[row0 + t];
        labConf[row0 + t] = tile[t][lab] * inv[t];   // same product as probsT store
    }
    const int shift = (rows == 64) ? 4 : 3;
    const int gq = 1 << shift;
    const int ng = NCLS << shift;
    for (int k = t; k < ng; k += 256) {
        int c = k >> shift, g = k & (gq - 1);
        int rr = g << 2;
        float4 o;
        o.x = tile[rr + 0][c] * inv[rr + 0];
        o.y = tile[rr + 1][c] * inv[rr + 1];
        o.z = tile[rr + 2][c] * inv[rr + 2];
        o.w = tile[rr + 3][c] * inv[rr + 3];
        *(float4*)(probsT + (size_t)c * NROWS + row0 + rr) = o;
    }
}

// Pass 2: per-class L1 histogram (top 12 used float bits), 2 bank-rotated LDS
// copies, non-atomic flush to private copy per blockIdx.x
__global__ __launch_bounds__(256) void k_hist1(const float4* __restrict__ probsT4,
                                               int* __restrict__ hist1p) {
    __shared__ int h[2][4096];   // 32 KB
    const int c = blockIdx.y, t = threadIdx.x;
    int4* hz = (int4*)&h[0][0];
    for (int i = t; i < 2048; i += 256) hz[i] = make_int4(0, 0, 0, 0);
    __syncthreads();
    const int copy = t & 1;
    const int rot = copy << 4;
    const size_t base = (size_t)c * NROWS4;
    const int start = blockIdx.x * CH1;
    const int end = min(NROWS4, start + CH1);
    for (int i = start + t; i < end; i += 256) {
        float4 v = probsT4[base + i];
        atomicAdd(&h[copy][((__float_as_uint(v.x) >> 18) + rot) & 4095], 1);
        atomicAdd(&h[copy][((__float_as_uint(v.y) >> 18) + rot) & 4095], 1);
        atomicAdd(&h[copy][((__float_as_uint(v.z) >> 18) + rot) & 4095], 1);
        atomicAdd(&h[copy][((__float_as_uint(v.w) >> 18) + rot) & 4095], 1);
    }
    __syncthreads();
    int* out = hist1p + ((size_t)blockIdx.x * NCLS + c) * 4096;
    for (int i = t; i < 4096; i += 256)
        out[i] = h[0][i] + h[1][(i + 16) & 4095];
}

// Select L1 bucket per rank target; parallel prefix (shfl), dedupe via owner[]
// (owner = LAST slot of a duplicate-target group, matching scan2's upper_bound)
__global__ __launch_bounds__(256) void k_sel1(const int* __restrict__ hist1p,
                                              int* __restrict__ tgt,
                                              int* __restrict__ below,
                                              int* __restrict__ owner) {
    __shared__ int wsum[4];
    __shared__ int stgt[NBINS];
    __shared__ int sbelow[NBINS];
    const int c = blockIdx.x, t = threadIdx.x;
    int4 acc[4] = {make_int4(0,0,0,0), make_int4(0,0,0,0),
                   make_int4(0,0,0,0), make_int4(0,0,0,0)};
    for (int k = 0; k < B1; ++k) {
        const int4* p = (const int4*)(hist1p + ((size_t)k * NCLS + c) * 4096) + t * 4;
        #pragma unroll
        for (int j = 0; j < 4; ++j) {
            int4 v = p[j];
            acc[j].x += v.x; acc[j].y += v.y; acc[j].z += v.z; acc[j].w += v.w;
        }
    }
    int loc[16];
    #pragma unroll
    for (int j = 0; j < 4; ++j) {
        loc[j * 4 + 0] = acc[j].x; loc[j * 4 + 1] = acc[j].y;
        loc[j * 4 + 2] = acc[j].z; loc[j * 4 + 3] = acc[j].w;
    }
    int s = 0;
    #pragma unroll
    for (int i = 0; i < 16; ++i) s += loc[i];
    // block-wide exclusive prefix of per-thread totals
    const int lane = t & 63, w = t >> 6;
    int incl = s;
    #pragma unroll
    for (int d = 1; d < 64; d <<= 1) {
        int n = __shfl_up(incl, d, 64);
        if (lane >= d) incl += n;
    }
    if (lane == 63) wsum[w] = incl;
    __syncthreads();
    int woff = 0;
    #pragma unroll
    for (int j = 0; j < 4; ++j) if (j < w) woff += wsum[j];
    const int cum0 = woff + incl - s;
    for (int b = 0; b < NBINS; ++b) {
        const int f = rank_target(b);
        int cc = cum0;
        #pragma unroll
        for (int i = 0; i < 16; ++i) {
            if (f >= cc && f < cc + loc[i]) { stgt[b] = t * 16 + i; sbelow[b] = cc; }
            cc += loc[i];
        }
    }
    __syncthreads();
    if (t == 0) {
        int ow = NBINS - 1;
        for (int b = NBINS - 1; b >= 0; --b) {
            if (b == NBINS - 1 || stgt[b] != stgt[b + 1]) ow = b;   // last-of-group
            owner[c * NBINS + b] = ow;
            tgt[c * NBINS + b] = stgt[b];
            below[c * NBINS + b] = sbelow[b];
        }
    }
}

// Pass 3: one scan produces (a) per-target-bucket sub-hists {n, sum v, sum v^2}
// and (b) equal-count SEGMENT sums {T, Q}, j = #{b : stg[b] <= bucket(v)}.
// Segment accumulators are THREAD-PRIVATE LDS slots segT[seg][tid]
// (bank = tid & 31 -> conflict-free for any per-lane seg mix; zero same-address
// collisions by construction).  atomicAdd on the private slot compiles to
// fire-and-forget ds_add_f32, avoiding the read-modify-write dependency chain
// the compiler would serialize (it can't disambiguate j-indexed addresses).
// Round-1 lesson: 32 shared slots -> wave-level same-address serialization
// (2.3M conflict cycles, 630 us).  Private slots remove the contention.
__global__ __launch_bounds__(256) void k_scan2(const float4* __restrict__ probsT4,
                                               const int* __restrict__ tgt,
                                               int* __restrict__ scan2p,
                                               float* __restrict__ segG) {
    __shared__ int stg[16];
    __shared__ unsigned char tbl[4096];
    __shared__ float segT[16][256];   // 16 KB, thread-private slots
    __shared__ float segQ[16][256];   // 16 KB
    __shared__ int hn[HSZ];
    __shared__ float hT[HSZ];
    __shared__ float hQ[HSZ];
    const int c = blockIdx.y, t = threadIdx.x;
    if (t < 16) stg[t] = (t < NBINS) ? tgt[c * NBINS + t] : 0x7FFFFFFF;
    #pragma unroll
    for (int j = 0; j < 16; ++j) { segT[j][t] = 0.f; segQ[j][t] = 0.f; }
    for (int i = t; i < HSZ; i += 256) { hn[i] = 0; hT[i] = 0.f; hQ[i] = 0.f; }
    __syncthreads();                      // stg ready
    // build bucket->segment table: thread t owns buckets [t*16, t*16+16)
    {
        const int k0 = t * 16;
        int j = 0;                        // j(k0) = #{stg <= k0}, 4-step upper search
        j += (stg[j + 7] <= k0) ? 8 : 0;
        j += (stg[j + 3] <= k0) ? 4 : 0;
        j += (stg[j + 1] <= k0) ? 2 : 0;
        j += (stg[j] <= k0) ? 1 : 0;
        for (int k = k0; k < k0 + 16; ++k) {
            while (j < NBINS && stg[j] <= k) ++j;
            tbl[k] = (unsigned char)j;
        }
    }
    __syncthreads();                      // j-values filled
    if (t < NBINS) tbl[stg[t]] |= 0x80;   // flag target buckets (dupes idempotent)
    __syncthreads();
    const size_t base = (size_t)c * NROWS4;
    const int start = blockIdx.x * CH2;
    const int end = min(NROWS4, start + CH2);
    for (int i = start + t; i < end; i += 256) {
        float4 v = probsT4[base + i];
        float val[4] = {v.x, v.y, v.z, v.w};
        unsigned bx[4] = {__float_as_uint(v.x), __float_as_uint(v.y),
                          __float_as_uint(v.z), __float_as_uint(v.w)};
        #pragma unroll
        for (int e = 0; e < 4; ++e) {
            const int k1 = (int)(bx[e] >> 18);
            const unsigned b8 = (unsigned)tbl[k1];
            const int j = (int)(b8 & 15u);
            atomicAdd(&segT[j][t], val[e]);              // ds_add_f32, private slot
            atomicAdd(&segQ[j][t], val[e] * val[e]);
            if (b8 & 0x80u) {             // inside a target bucket: sub-histogram
                int sub = (j - 1) * NSUB + (int)((bx[e] >> 12) & (NSUB - 1));
                atomicAdd(&hn[sub], 1);
                atomicAdd(&hT[sub], val[e]);
                atomicAdd(&hQ[sub], val[e] * val[e]);
            }
        }
    }
    __syncthreads();
    // flush private sub-hist copy: [blk*NCLS+c][3][960]
    int* on = scan2p + ((size_t)(blockIdx.x * NCLS + c) * 3) * HSZ;
    float* oT = (float*)(on + HSZ);
    float* oQ = (float*)(on + 2 * HSZ);
    for (int i = t; i < HSZ; i += 256) { on[i] = hn[i]; oT[i] = hT[i]; oQ[i] = hQ[i]; }
    // reduce per-thread segment slots -> block totals -> global atomics
    {
        const int j = t >> 4, p = t & 15;    // 16 threads per segment
        float sT = 0.f, sQ = 0.f;
        #pragma unroll
        for (int i = 0; i < 16; ++i) {
            sT += segT[j][p * 16 + i];
            sQ += segQ[j][p * 16 + i];
        }
        #pragma unroll
        for (int o = 8; o; o >>= 1) {
            sT += __shfl_xor(sT, o, 64);
            sQ += __shfl_xor(sQ, o, 64);
        }
        if (p == 0) {
            atomicAdd(&segG[c * 32 + 2 * j], sT);
            atomicAdd(&segG[c * 32 + 2 * j + 1], sQ);
        }
    }
}

// Select sub-bucket (single wave, shfl prefix over 64 subs); cumulative {N,T,Q}
// at the boundary: cumT[b] = sum_{j<=b} segT[j] + sub-prefix (assembled in double)
__global__ __launch_bounds__(64) void k_sel2(const int* __restrict__ scan2p,
                                             const int* __restrict__ tgt,
                                             const int* __restrict__ below,
                                             const int* __restrict__ owner,
                                             const float* __restrict__ segG,
                                             float* __restrict__ bounds,
                                             int* __restrict__ cumN,
                                             double* __restrict__ cumT,
                                             double* __restrict__ cumQ) {
    const int b = blockIdx.x, c = blockIdx.y, t = threadIdx.x;   // t < 64
    const int ow = owner[c * NBINS + b];
    int nj = 0; float Tj = 0.f, Qj = 0.f;
    for (int k = 0; k < B2; ++k) {
        const int* p = scan2p + ((size_t)(k * NCLS + c) * 3) * HSZ + ow * NSUB + t;
        nj += p[0];
        Tj += ((const float*)p)[HSZ];
        Qj += ((const float*)p)[2 * HSZ];
    }
    const int own = nj;
    #pragma unroll
    for (int d = 1; d < 64; d <<= 1) {
        int nn = __shfl_up(nj, d, 64);
        float TT = __shfl_up(Tj, d, 64);
        float QQ = __shfl_up(Qj, d, 64);
        if (t >= d) { nj += nn; Tj += TT; Qj += QQ; }
    }
    const int bel = below[c * NBINS + b];
    const int lr = rank_target(b) - bel;
    if (lr >= nj - own && lr < nj) {
        unsigned bits = ((unsigned)tgt[c * NBINS + b] << 18) | ((unsigned)t << 12) | 0xFFFu;
        bounds[c * NBINS + b] = __uint_as_float(bits);
        cumN[c * NBINS + b] = bel + nj;
        double A = 0.0, Qd = 0.0;
        for (int j = 0; j <= b; ++j) {
            A  += (double)segG[c * 32 + 2 * j];
            Qd += (double)segG[c * 32 + 2 * j + 1];
        }
        cumT[c * NBINS + b] = A + (double)Tj;
        cumQ[c * NBINS + b] = Qd + (double)Qj;
    }
}

// Pass 4: label correction from the compact labConf array (coalesced), LDS-staged
// bounds table + LDS-staged accumulator, one filtered global-atomic flush per block
__global__ __launch_bounds__(256) void k_label(const float* __restrict__ labConf,
                                               const int* __restrict__ labels,
                                               const float* __restrict__ bounds,
                                               float* __restrict__ accLab) {
    __shared__ float sbd[NCLS * NBINS];        // 6 KB
    __shared__ float sacc[NCLS * NBINS * 2];   // 12 KB
    const int t = threadIdx.x;
    for (int i = t; i < NCLS * NBINS; i += 256) sbd[i] = bounds[i];
    for (int i = t; i < NCLS * NBINS * 2; i += 256) sacc[i] = 0.f;
    __syncthreads();
    for (int n = blockIdx.x * 256 + t; n < NROWS; n += gridDim.x * 256) {
        const int c = labels[n];
        const float conf = labConf[n];
        const float* bd = sbd + c * NBINS;
        if (conf > bd[0]) {
            int idx = 0;
            #pragma unroll
            for (int b = 1; b < NBINS; ++b) idx += (conf > bd[b]) ? 1 : 0;
            atomicAdd(&sacc[(c * NBINS + idx) * 2 + 0], 1.0f);
            atomicAdd(&sacc[(c * NBINS + idx) * 2 + 1], conf);
        }
    }
    __syncthreads();
    for (int i = t; i < NCLS * NBINS * 2; i += 256)
        if (sacc[i] != 0.f) atomicAdd(&accLab[i], sacc[i]);
}

// Pass 5: closed-form LOO combine in double (totals from segment sums)
__global__ __launch_bounds__(256) void k_final(const float* __restrict__ segG,
                                               const int* __restrict__ cumN,
                                               const double* __restrict__ cumT,
                                               const double* __restrict__ cumQ,
                                               const float* __restrict__ accLab,
                                               float* __restrict__ out) {
    __shared__ double red[256];
    const int t = threadIdx.x;
    double local = 0.0;
    for (int k = t; k < NCLS * NBINS; k += 256) {
        int c = k / NBINS, b = k - c * NBINS;
        double n, T, Q;
        if (b < NBINS - 1) {
            n = (double)(cumN[k + 1] - cumN[k]);
            T = cumT[k + 1] - cumT[k];
            Q = cumQ[k + 1] - cumQ[k];
        } else {
            double sT = 0.0, sQ = 0.0;
            for (int j = 0; j < 16; ++j) {
                sT += (double)segG[c * 32 + 2 * j];
                sQ += (double)segG[c * 32 + 2 * j + 1];
            }
            n = (double)(NROWS - cumN[k]);
            T = sT - cumT[k];
            Q = sQ - cumQ[k];
        }
        double S = accLab[k * 2 + 0], T1 = accLab[k * 2 + 1];
        if (n > 1.5) {
            double inv = 1.0 / (n - 1.0);
            double a0 = S * inv, a1 = (S - 1.0) * inv;
            local += Q - 2.0 * a0 * T + 2.0 * T1 * inv + (n - S) * a0 * a0 + S * a1 * a1;
        }
    }
    red[t] = local;
    __syncthreads();
    for (int s = 128; s; s >>= 1) {
        if (t < s) red[t] += red[t + s];
        __syncthreads();
    }
    if (t == 0) out[0] = (float)(red[0] / ((double)NROWS * (double)NCLS));
}

extern "C" void kernel_launch(void* const* d_in, const int* in_sizes, int n_in,
                              void* d_out, int out_size, void* d_ws, size_t ws_size,
                              hipStream_t stream) {
    const float* logits = (const float*)d_in[0];
    const int* labels = (const int*)d_in[1];
    float* out = (float*)d_out;
    char* ws = (char*)d_ws;
    size_t off = 0;
    auto alloc = [&](size_t bytes) -> void* {
        off = (off + 255) & ~(size_t)255;
        void* p = ws + off;
        off += bytes;
        return p;
    };
    float* probsT = (float*)alloc((size_t)NCLS * NROWS * 4);               // 200 MB
    // shared region: hist1p (hist1->sel1) then reused as scan2p (scan2->sel2)
    size_t h1bytes = (size_t)B1 * NCLS * 4096 * 4;                         // 22.9 MB
    size_t s2bytes = (size_t)B2 * NCLS * 3 * HSZ * 4;                      // 18.4 MB
    int* hist1p = (int*)alloc(h1bytes > s2bytes ? h1bytes : s2bytes);
    int* scan2p = hist1p;
    float* labConf = (float*)alloc((size_t)NROWS * 4);                     // 2 MB
    // --- zeroed region (contiguous, single small memset) ---
    char* zbase = ws + ((off + 255) & ~(size_t)255);
    float* segG   = (float*)alloc((size_t)NCLS * 32 * 4);                  // [c][16]{T,Q}
    float* accLab = (float*)alloc((size_t)NCLS * NBINS * 2 * 4);
    size_t zlen = (size_t)((ws + off) - zbase);
    // --- written-before-read region ---
    int*    tgt     = (int*)alloc((size_t)NCLS * NBINS * 4);
    int*    below   = (int*)alloc((size_t)NCLS * NBINS * 4);
    int*    owner   = (int*)alloc((size_t)NCLS * NBINS * 4);
    float*  bounds  = (float*)alloc((size_t)NCLS * NBINS * 4);
    int*    cumN    = (int*)alloc((size_t)NCLS * NBINS * 4);
    double* cumT    = (double*)alloc((size_t)NCLS * NBINS * 8);
    double* cumQ    = (double*)alloc((size_t)NCLS * NBINS * 8);
    if (off > ws_size) {
        hipMemsetAsync(d_out, 0xFF, 4, stream);   // NaN sentinel
        return;
    }
    hipMemsetAsync(zbase, 0, zlen, stream);

    k_softmax_t<<<(NROWS + 63) / 64, 256, 0, stream>>>(logits, labels, probsT, labConf);
    k_hist1<<<dim3(B1, NCLS), 256, 0, stream>>>((const float4*)probsT, hist1p);
    k_sel1<<<NCLS, 256, 0, stream>>>(hist1p, tgt, below, owner);
    k_scan2<<<dim3(B2, NCLS), 256, 0, stream>>>((const float4*)probsT, tgt, scan2p, segG);
    k_sel2<<<dim3(NBINS, NCLS), 64, 0, stream>>>(scan2p, tgt, below, owner, segG,
                                                 bounds, cumN, cumT, cumQ);
    k_label<<<128, 256, 0, stream>>>(labConf, labels, bounds, accLab);
    k_final<<<1, 256, 0, stream>>>(segG, cumN, cumT, cumQ, accLab, out);
}

// Round 3
// 532.685 us; speedup vs baseline: 1.9525x; 1.9525x over previous
//
#include <hip/hip_runtime.h>
#include <stdint.h>

#define NROWS 500000
#define NROWS4 125000
#define NCLS 100
#define NBINS 15
#define NSUB 64          // sub-bucket = 4096 ULP; ~70 elems/sub near mode -> rank err << tolerance
#define B1 14
#define CH1 8929         // ceil(125000/14) float4s per hist1 block
#define B2 28
#define CH2 4465         // ceil(125000/28) float4s per scan2 block
#define HSZ (NBINS * NSUB)   // 960

__device__ __forceinline__ int rank_target(int b) {
    if (b == 0) return 0;
    const float step = 500000.0f / 15.0f;   // float32-rounded, mimics jnp.linspace
    return (int)floorf((float)b * step);
}

__device__ __forceinline__ float wave_sum(float v) {
    #pragma unroll
    for (int o = 32; o; o >>= 1) v += __shfl_xor(v, o, 64);
    return v;
}

// Pass 1: row softmax of logits [N][C], write transposed probsT [C][N].
// Also emits labConf[n] = prob of the labeled class (bit-identical product to
// the stored probsT value), so k_label never has to gather probsT.
__global__ __launch_bounds__(256) void k_softmax_t(const float* __restrict__ logits,
                                                   const int* __restrict__ labels,
                                                   float* __restrict__ probsT,
                                                   float* __restrict__ labConf) {
    __shared__ float tile[64][101];
    __shared__ float red[256];
    __shared__ float mx[64];
    __shared__ float inv[64];
    const int row0 = blockIdx.x * 64;
    const int rows = min(64, NROWS - row0);
    const int t = threadIdx.x;
    const int total = rows * NCLS;
    for (int k = t; k < total; k += 256) {
        int r = k / NCLS, c = k - r * NCLS;
        tile[r][c] = logits[(size_t)(row0 + r) * NCLS + c];
    }
    __syncthreads();
    const int r = t >> 2, q = t & 3;   // 4 threads per row
    if (r < rows) {
        float m = -1e30f;
        #pragma unroll
        for (int c = 0; c < 25; ++c) m = fmaxf(m, tile[r][q * 25 + c]);
        red[t] = m;
    }
    __syncthreads();
    if (r < rows && q == 0)
        mx[r] = fmaxf(fmaxf(red[t], red[t + 1]), fmaxf(red[t + 2], red[t + 3]));
    __syncthreads();
    if (r < rows) {
        float m = mx[r], s = 0.f;
        #pragma unroll
        for (int c = 0; c < 25; ++c) {
            float e = __expf(tile[r][q * 25 + c] - m);
            tile[r][q * 25 + c] = e;
            s += e;
        }
        red[t] = s;
    }
    __syncthreads();
    if (r < rows && q == 0)
        inv[r] = 1.0f / (red[t] + red[t + 1] + red[t + 2] + red[t + 3]);
    __syncthreads();
    if (t < rows) {
        const int lab = labels[row0 + t];
        labConf[row0 + t] = tile[t][lab] * inv[t];   // same product as probsT store
    }
    const int shift = (rows == 64) ? 4 : 3;
    const int gq = 1 << shift;
    const int ng = NCLS << shift;
    for (int k = t; k < ng; k += 256) {
        int c = k >> shift, g = k & (gq - 1);
        int rr = g << 2;
        float4 o;
        o.x = tile[rr + 0][c] * inv[rr + 0];
        o.y = tile[rr + 1][c] * inv[rr + 1];
        o.z = tile[rr + 2][c] * inv[rr + 2];
        o.w = tile[rr + 3][c] * inv[rr + 3];
        *(float4*)(probsT + (size_t)c * NROWS + row0 + rr) = o;
    }
}

// Pass 2: per-class L1 histogram (top 12 used float bits), 2 bank-rotated LDS
// copies, non-atomic flush to private copy per blockIdx.x
__global__ __launch_bounds__(256) void k_hist1(const float4* __restrict__ probsT4,
                                               int* __restrict__ hist1p) {
    __shared__ int h[2][4096];   // 32 KB
    const int c = blockIdx.y, t = threadIdx.x;
    int4* hz = (int4*)&h[0][0];
    for (int i = t; i < 2048; i += 256) hz[i] = make_int4(0, 0, 0, 0);
    __syncthreads();
    const int copy = t & 1;
    const int rot = copy << 4;
    const size_t base = (size_t)c * NROWS4;
    const int start = blockIdx.x * CH1;
    const int end = min(NROWS4, start + CH1);
    for (int i = start + t; i < end; i += 256) {
        float4 v = probsT4[base + i];
        atomicAdd(&h[copy][((__float_as_uint(v.x) >> 18) + rot) & 4095], 1);
        atomicAdd(&h[copy][((__float_as_uint(v.y) >> 18) + rot) & 4095], 1);
        atomicAdd(&h[copy][((__float_as_uint(v.z) >> 18) + rot) & 4095], 1);
        atomicAdd(&h[copy][((__float_as_uint(v.w) >> 18) + rot) & 4095], 1);
    }
    __syncthreads();
    int* out = hist1p + ((size_t)blockIdx.x * NCLS + c) * 4096;
    for (int i = t; i < 4096; i += 256)
        out[i] = h[0][i] + h[1][(i + 16) & 4095];
}

// Select L1 bucket per rank target; parallel prefix (shfl), dedupe via owner[]
// (owner = FIRST slot of a duplicate-target group, matching scan2's lower_bound);
// emit edgeArr = largest float strictly below the target bucket
__global__ __launch_bounds__(256) void k_sel1(const int* __restrict__ hist1p,
                                              int* __restrict__ tgt,
                                              int* __restrict__ below,
                                              int* __restrict__ owner,
                                              float* __restrict__ edgeArr) {
    __shared__ int wsum[4];
    __shared__ int stgt[NBINS];
    __shared__ int sbelow[NBINS];
    const int c = blockIdx.x, t = threadIdx.x;
    int4 acc[4] = {make_int4(0,0,0,0), make_int4(0,0,0,0),
                   make_int4(0,0,0,0), make_int4(0,0,0,0)};
    for (int k = 0; k < B1; ++k) {
        const int4* p = (const int4*)(hist1p + ((size_t)k * NCLS + c) * 4096) + t * 4;
        #pragma unroll
        for (int j = 0; j < 4; ++j) {
            int4 v = p[j];
            acc[j].x += v.x; acc[j].y += v.y; acc[j].z += v.z; acc[j].w += v.w;
        }
    }
    int loc[16];
    #pragma unroll
    for (int j = 0; j < 4; ++j) {
        loc[j * 4 + 0] = acc[j].x; loc[j * 4 + 1] = acc[j].y;
        loc[j * 4 + 2] = acc[j].z; loc[j * 4 + 3] = acc[j].w;
    }
    int s = 0;
    #pragma unroll
    for (int i = 0; i < 16; ++i) s += loc[i];
    // block-wide exclusive prefix of per-thread totals
    const int lane = t & 63, w = t >> 6;
    int incl = s;
    #pragma unroll
    for (int d = 1; d < 64; d <<= 1) {
        int n = __shfl_up(incl, d, 64);
        if (lane >= d) incl += n;
    }
    if (lane == 63) wsum[w] = incl;
    __syncthreads();
    int woff = 0;
    #pragma unroll
    for (int j = 0; j < 4; ++j) if (j < w) woff += wsum[j];
    const int cum0 = woff + incl - s;
    for (int b = 0; b < NBINS; ++b) {
        const int f = rank_target(b);
        int cc = cum0;
        #pragma unroll
        for (int i = 0; i < 16; ++i) {
            if (f >= cc && f < cc + loc[i]) { stgt[b] = t * 16 + i; sbelow[b] = cc; }
            cc += loc[i];
        }
    }
    __syncthreads();
    if (t == 0) {
        int ow = 0;
        for (int b = 0; b < NBINS; ++b) {
            if (b == 0 || stgt[b] != stgt[b - 1]) ow = b;
            owner[c * NBINS + b] = ow;
            tgt[c * NBINS + b] = stgt[b];
            below[c * NBINS + b] = sbelow[b];
            unsigned tg = (unsigned)stgt[b];
            edgeArr[c * NBINS + b] = tg ? __uint_as_float((tg << 18) - 1u) : 0.0f;
        }
    }
}

// Pass 3 (round-0 structure, widened grid): one scan produces (a) per-target-
// bucket sub-hists {n, sum v, sum v^2} at 64 subs and (b) min-trick cumulative
// sums vs the L1 bucket low edge + class totals (accA).  The min-trick is pure
// VALU on 15 register accumulator pairs -> VALU-issue-bound (~383 cyc/wave-iter,
// known from round-0 counters).  Rounds 1-2 showed a per-element wide-table LDS
// gather + atomics runs 4.5x SLOWER (latency-exposed); keep register math.
// accA per class: [0..14]=sum min(v,edge_b), [15..29]=sum min^2, [30]=sumT, [31]=sumQ
__global__ __launch_bounds__(256) void k_scan2(const float4* __restrict__ probsT4,
                                               const int* __restrict__ tgt,
                                               const float* __restrict__ edgeArr,
                                               int* __restrict__ scan2p,
                                               float* __restrict__ accA) {
    __shared__ int stg[16];
    __shared__ int hn[HSZ];
    __shared__ float hT[HSZ];
    __shared__ float hQ[HSZ];
    __shared__ float lred[4][32];
    const int c = blockIdx.y, t = threadIdx.x;
    if (t < 16) stg[t] = (t < NBINS) ? tgt[c * NBINS + t] : 0x7FFFFFFF;
    for (int i = t; i < HSZ; i += 256) { hn[i] = 0; hT[i] = 0.f; hQ[i] = 0.f; }
    float edge[NBINS];
    #pragma unroll
    for (int b = 0; b < NBINS; ++b) edge[b] = edgeArr[c * NBINS + b];
    float mt[NBINS], mq[NBINS];
    #pragma unroll
    for (int b = 0; b < NBINS; ++b) { mt[b] = 0.f; mq[b] = 0.f; }
    float tT = 0.f, tQ = 0.f;
    __syncthreads();
    const size_t base = (size_t)c * NROWS4;
    const int start = blockIdx.x * CH2;
    const int end = min(NROWS4, start + CH2);
    for (int i = start + t; i < end; i += 256) {
        float4 v = probsT4[base + i];
        tT += (v.x + v.y) + (v.z + v.w);
        tQ = fmaf(v.x, v.x, fmaf(v.y, v.y, fmaf(v.z, v.z, fmaf(v.w, v.w, tQ))));
        #pragma unroll
        for (int b = 0; b < NBINS; ++b) {
            float m0 = fminf(v.x, edge[b]), m1 = fminf(v.y, edge[b]);
            float m2 = fminf(v.z, edge[b]), m3 = fminf(v.w, edge[b]);
            mt[b] += (m0 + m1) + (m2 + m3);
            mq[b] = fmaf(m0, m0, fmaf(m1, m1, fmaf(m2, m2, fmaf(m3, m3, mq[b]))));
        }
        float val[4] = {v.x, v.y, v.z, v.w};
        unsigned bx[4] = {__float_as_uint(v.x), __float_as_uint(v.y),
                          __float_as_uint(v.z), __float_as_uint(v.w)};
        #pragma unroll
        for (int e = 0; e < 4; ++e) {
            int k1 = (int)(bx[e] >> 18);
            int idx = 0;                      // lower_bound over sorted stg (dupes -> first slot)
            idx += (stg[idx + 7] < k1) ? 8 : 0;
            idx += (stg[idx + 3] < k1) ? 4 : 0;
            idx += (stg[idx + 1] < k1) ? 2 : 0;
            idx += (stg[idx] < k1) ? 1 : 0;
            if (idx < NBINS && stg[idx] == k1) {
                int sub = idx * NSUB + ((bx[e] >> 12) & (NSUB - 1));
                atomicAdd(&hn[sub], 1);
                atomicAdd(&hT[sub], val[e]);
                atomicAdd(&hQ[sub], val[e] * val[e]);
            }
        }
    }
    __syncthreads();
    // flush private copy: [blk*NCLS+c][3][960]
    int* on = scan2p + ((size_t)(blockIdx.x * NCLS + c) * 3) * HSZ;
    float* oT = (float*)(on + HSZ);
    float* oQ = (float*)(on + 2 * HSZ);
    for (int i = t; i < HSZ; i += 256) { on[i] = hn[i]; oT[i] = hT[i]; oQ[i] = hQ[i]; }
    // reduce register accumulators into accA
    const int w = t >> 6, lane = t & 63;
    float vals[32];
    #pragma unroll
    for (int b = 0; b < NBINS; ++b) { vals[b] = mt[b]; vals[NBINS + b] = mq[b]; }
    vals[30] = tT; vals[31] = tQ;
    #pragma unroll
    for (int j = 0; j < 32; ++j) vals[j] = wave_sum(vals[j]);
    if (lane == 0) {
        #pragma unroll
        for (int j = 0; j < 32; ++j) lred[w][j] = vals[j];
    }
    __syncthreads();
    if (t < 32) {
        float s = lred[0][t] + lred[1][t] + lred[2][t] + lred[3][t];
        atomicAdd(&accA[c * 32 + t], s);
    }
}

// Select sub-bucket (single wave, shfl prefix over 64 subs); assemble exact
// cumulative {N, T, Q} at the boundary in double
__global__ __launch_bounds__(64) void k_sel2(const int* __restrict__ scan2p,
                                             const int* __restrict__ tgt,
                                             const int* __restrict__ below,
                                             const int* __restrict__ owner,
                                             const float* __restrict__ edgeArr,
                                             const float* __restrict__ accA,
                                             float* __restrict__ bounds,
                                             int* __restrict__ cumN,
                                             double* __restrict__ cumT,
                                             double* __restrict__ cumQ) {
    const int b = blockIdx.x, c = blockIdx.y, t = threadIdx.x;   // t < 64
    const int ow = owner[c * NBINS + b];
    int nj = 0; float Tj = 0.f, Qj = 0.f;
    for (int k = 0; k < B2; ++k) {
        const int* p = scan2p + ((size_t)(k * NCLS + c) * 3) * HSZ + ow * NSUB + t;
        nj += p[0];
        Tj += ((const float*)p)[HSZ];
        Qj += ((const float*)p)[2 * HSZ];
    }
    const int own = nj;
    #pragma unroll
    for (int d = 1; d < 64; d <<= 1) {
        int nn = __shfl_up(nj, d, 64);
        float TT = __shfl_up(Tj, d, 64);
        float QQ = __shfl_up(Qj, d, 64);
        if (t >= d) { nj += nn; Tj += TT; Qj += QQ; }
    }
    const int bel = below[c * NBINS + b];
    const int lr = rank_target(b) - bel;
    if (lr >= nj - own && lr < nj) {
        unsigned bits = ((unsigned)tgt[c * NBINS + b] << 18) | ((unsigned)t << 12) | 0xFFFu;
        bounds[c * NBINS + b] = __uint_as_float(bits);
        cumN[c * NBINS + b] = bel + nj;
        double edge = (double)edgeArr[c * NBINS + b];
        double above = (double)(NROWS - bel);
        cumT[c * NBINS + b] = ((double)accA[c * 32 + b] - edge * above) + (double)Tj;
        cumQ[c * NBINS + b] = ((double)accA[c * 32 + NBINS + b] - edge * edge * above) + (double)Qj;
    }
}

// Pass 4: label correction from the compact labConf array (coalesced), LDS-staged
// bounds table + LDS-staged accumulator, one filtered global-atomic flush per block
__global__ __launch_bounds__(256) void k_label(const float* __restrict__ labConf,
                                               const int* __restrict__ labels,
                                               const float* __restrict__ bounds,
                                               float* __restrict__ accLab) {
    __shared__ float sbd[NCLS * NBINS];        // 6 KB
    __shared__ float sacc[NCLS * NBINS * 2];   // 12 KB
    const int t = threadIdx.x;
    for (int i = t; i < NCLS * NBINS; i += 256) sbd[i] = bounds[i];
    for (int i = t; i < NCLS * NBINS * 2; i += 256) sacc[i] = 0.f;
    __syncthreads();
    for (int n = blockIdx.x * 256 + t; n < NROWS; n += gridDim.x * 256) {
        const int c = labels[n];
        const float conf = labConf[n];
        const float* bd = sbd + c * NBINS;
        if (conf > bd[0]) {
            int idx = 0;
            #pragma unroll
            for (int b = 1; b < NBINS; ++b) idx += (conf > bd[b]) ? 1 : 0;
            atomicAdd(&sacc[(c * NBINS + idx) * 2 + 0], 1.0f);
            atomicAdd(&sacc[(c * NBINS + idx) * 2 + 1], conf);
        }
    }
    __syncthreads();
    for (int i = t; i < NCLS * NBINS * 2; i += 256)
        if (sacc[i] != 0.f) atomicAdd(&accLab[i], sacc[i]);
}

// Pass 5: closed-form LOO combine in double
__global__ __launch_bounds__(256) void k_final(const float* __restrict__ accA,
                                               const int* __restrict__ cumN,
                                               const double* __restrict__ cumT,
                                               const double* __restrict__ cumQ,
                                               const float* __restrict__ accLab,
                                               float* __restrict__ out) {
    __shared__ double red[256];
    const int t = threadIdx.x;
    double local = 0.0;
    for (int k = t; k < NCLS * NBINS; k += 256) {
        int c = k / NBINS, b = k - c * NBINS;
        double n, T, Q;
        if (b < NBINS - 1) {
            n = (double)(cumN[k + 1] - cumN[k]);
            T = cumT[k + 1] - cumT[k];
            Q = cumQ[k + 1] - cumQ[k];
        } else {
            n = (double)(NROWS - cumN[k]);
            T = (double)accA[c * 32 + 30] - cumT[k];
            Q = (double)accA[c * 32 + 31] - cumQ[k];
        }
        double S = accLab[k * 2 + 0], T1 = accLab[k * 2 + 1];
        if (n > 1.5) {
            double inv = 1.0 / (n - 1.0);
            double a0 = S * inv, a1 = (S - 1.0) * inv;
            local += Q - 2.0 * a0 * T + 2.0 * T1 * inv + (n - S) * a0 * a0 + S * a1 * a1;
        }
    }
    red[t] = local;
    __syncthreads();
    for (int s = 128; s; s >>= 1) {
        if (t < s) red[t] += red[t + s];
        __syncthreads();
    }
    if (t == 0) out[0] = (float)(red[0] / ((double)NROWS * (double)NCLS));
}

extern "C" void kernel_launch(void* const* d_in, const int* in_sizes, int n_in,
                              void* d_out, int out_size, void* d_ws, size_t ws_size,
                              hipStream_t stream) {
    const float* logits = (const float*)d_in[0];
    const int* labels = (const int*)d_in[1];
    float* out = (float*)d_out;
    char* ws = (char*)d_ws;
    size_t off = 0;
    auto alloc = [&](size_t bytes) -> void* {
        off = (off + 255) & ~(size_t)255;
        void* p = ws + off;
        off += bytes;
        return p;
    };
    float* probsT = (float*)alloc((size_t)NCLS * NROWS * 4);               // 200 MB
    // shared region: hist1p (hist1->sel1) then reused as scan2p (scan2->sel2)
    size_t h1bytes = (size_t)B1 * NCLS * 4096 * 4;                         // 22.9 MB
    size_t s2bytes = (size_t)B2 * NCLS * 3 * HSZ * 4;                      // 32.3 MB
    int* hist1p = (int*)alloc(h1bytes > s2bytes ? h1bytes : s2bytes);
    int* scan2p = hist1p;
    float* labConf = (float*)alloc((size_t)NROWS * 4);                     // 2 MB
    // --- zeroed region (contiguous, single small memset) ---
    char* zbase = ws + ((off + 255) & ~(size_t)255);
    float* accA   = (float*)alloc((size_t)NCLS * 32 * 4);
    float* accLab = (float*)alloc((size_t)NCLS * NBINS * 2 * 4);
    size_t zlen = (size_t)((ws + off) - zbase);
    // --- written-before-read region ---
    int*    tgt     = (int*)alloc((size_t)NCLS * NBINS * 4);
    int*    below   = (int*)alloc((size_t)NCLS * NBINS * 4);
    int*    owner   = (int*)alloc((size_t)NCLS * NBINS * 4);
    float*  edgeArr = (float*)alloc((size_t)NCLS * NBINS * 4);
    float*  bounds  = (float*)alloc((size_t)NCLS * NBINS * 4);
    int*    cumN    = (int*)alloc((size_t)NCLS * NBINS * 4);
    double* cumT    = (double*)alloc((size_t)NCLS * NBINS * 8);
    double* cumQ    = (double*)alloc((size_t)NCLS * NBINS * 8);
    if (off > ws_size) {
        hipMemsetAsync(d_out, 0xFF, 4, stream);   // NaN sentinel
        return;
    }
    hipMemsetAsync(zbase, 0, zlen, stream);

    k_softmax_t<<<(NROWS + 63) / 64, 256, 0, stream>>>(logits, labels, probsT, labConf);
    k_hist1<<<dim3(B1, NCLS), 256, 0, stream>>>((const float4*)probsT, hist1p);
    k_sel1<<<NCLS, 256, 0, stream>>>(hist1p, tgt, below, owner, edgeArr);
    k_scan2<<<dim3(B2, NCLS), 256, 0, stream>>>((const float4*)probsT, tgt, edgeArr,
                                                scan2p, accA);
    k_sel2<<<dim3(NBINS, NCLS), 64, 0, stream>>>(scan2p, tgt, below, owner, edgeArr,
                                                 accA, bounds, cumN, cumT, cumQ);
    k_label<<<128, 256, 0, stream>>>(labConf, labels, bounds, accLab);
    k_final<<<1, 256, 0, stream>>>(accA, cumN, cumT, cumQ, accLab, out);
}

// Round 4
// 478.034 us; speedup vs baseline: 2.1758x; 1.1143x over previous
//
#include <hip/hip_runtime.h>
#include <stdint.h>

#define NROWS 500000
#define NROWS4 125000
#define NCLS 100
#define NBINS 15
#define NSUB 64          // sub-bucket = 4096 ULP; ~70 elems/sub near mode -> rank err << tolerance
#define B1 14
#define CH1 8929         // ceil(125000/14) float4s per hist1 block
#define B2 28
#define CH2 4465         // ceil(125000/28) float4s per scan2 block
#define HSZ (NBINS * NSUB)   // 960
#define FPS 16777216.0f      // 2^24 fixed-point scale (u32 slot: 144 elems * 2^24 = 2.4e9 < 4.3e9)
#define FPI (1.0 / 16777216.0)

__device__ __forceinline__ int rank_target(int b) {
    if (b == 0) return 0;
    const float step = 500000.0f / 15.0f;   // float32-rounded, mimics jnp.linspace
    return (int)floorf((float)b * step);
}

// Pass 1: row softmax of logits [N][C], write transposed probsT [C][N].
// Also emits labConf[n] = prob of the labeled class (bit-identical product to
// the stored probsT value), so k_label never has to gather probsT.
__global__ __launch_bounds__(256) void k_softmax_t(const float* __restrict__ logits,
                                                   const int* __restrict__ labels,
                                                   float* __restrict__ probsT,
                                                   float* __restrict__ labConf) {
    __shared__ float tile[64][101];
    __shared__ float red[256];
    __shared__ float mx[64];
    __shared__ float inv[64];
    const int row0 = blockIdx.x * 64;
    const int rows = min(64, NROWS - row0);
    const int t = threadIdx.x;
    const int total = rows * NCLS;
    for (int k = t; k < total; k += 256) {
        int r = k / NCLS, c = k - r * NCLS;
        tile[r][c] = logits[(size_t)(row0 + r) * NCLS + c];
    }
    __syncthreads();
    const int r = t >> 2, q = t & 3;   // 4 threads per row
    if (r < rows) {
        float m = -1e30f;
        #pragma unroll
        for (int c = 0; c < 25; ++c) m = fmaxf(m, tile[r][q * 25 + c]);
        red[t] = m;
    }
    __syncthreads();
    if (r < rows && q == 0)
        mx[r] = fmaxf(fmaxf(red[t], red[t + 1]), fmaxf(red[t + 2], red[t + 3]));
    __syncthreads();
    if (r < rows) {
        float m = mx[r], s = 0.f;
        #pragma unroll
        for (int c = 0; c < 25; ++c) {
            float e = __expf(tile[r][q * 25 + c] - m);
            tile[r][q * 25 + c] = e;
            s += e;
        }
        red[t] = s;
    }
    __syncthreads();
    if (r < rows && q == 0)
        inv[r] = 1.0f / (red[t] + red[t + 1] + red[t + 2] + red[t + 3]);
    __syncthreads();
    if (t < rows) {
        const int lab = labels[row0 + t];
        labConf[row0 + t] = tile[t][lab] * inv[t];   // same product as probsT store
    }
    const int shift = (rows == 64) ? 4 : 3;
    const int gq = 1 << shift;
    const int ng = NCLS << shift;
    for (int k = t; k < ng; k += 256) {
        int c = k >> shift, g = k & (gq - 1);
        int rr = g << 2;
        float4 o;
        o.x = tile[rr + 0][c] * inv[rr + 0];
        o.y = tile[rr + 1][c] * inv[rr + 1];
        o.z = tile[rr + 2][c] * inv[rr + 2];
        o.w = tile[rr + 3][c] * inv[rr + 3];
        *(float4*)(probsT + (size_t)c * NROWS + row0 + rr) = o;
    }
}

// Pass 2: per-class L1 histogram (top 12 used float bits), 2 bank-rotated LDS
// copies, non-atomic flush to private copy per blockIdx.x.  Int atomics only
// (ds_add_u32 native; this kernel was never a problem).
__global__ __launch_bounds__(256) void k_hist1(const float4* __restrict__ probsT4,
                                               int* __restrict__ hist1p) {
    __shared__ int h[2][4096];   // 32 KB
    const int c = blockIdx.y, t = threadIdx.x;
    int4* hz = (int4*)&h[0][0];
    for (int i = t; i < 2048; i += 256) hz[i] = make_int4(0, 0, 0, 0);
    __syncthreads();
    const int copy = t & 1;
    const int rot = copy << 4;
    const size_t base = (size_t)c * NROWS4;
    const int start = blockIdx.x * CH1;
    const int end = min(NROWS4, start + CH1);
    for (int i = start + t; i < end; i += 256) {
        float4 v = probsT4[base + i];
        atomicAdd(&h[copy][((__float_as_uint(v.x) >> 18) + rot) & 4095], 1);
        atomicAdd(&h[copy][((__float_as_uint(v.y) >> 18) + rot) & 4095], 1);
        atomicAdd(&h[copy][((__float_as_uint(v.z) >> 18) + rot) & 4095], 1);
        atomicAdd(&h[copy][((__float_as_uint(v.w) >> 18) + rot) & 4095], 1);
    }
    __syncthreads();
    int* out = hist1p + ((size_t)blockIdx.x * NCLS + c) * 4096;
    for (int i = t; i < 4096; i += 256)
        out[i] = h[0][i] + h[1][(i + 16) & 4095];
}

// Select L1 bucket per rank target; parallel prefix (shfl), dedupe via owner[]
// (owner = LAST slot of a duplicate-target group, matching scan2's upper_bound
// table semantics; this pairing passed exact in rounds 1-2)
__global__ __launch_bounds__(256) void k_sel1(const int* __restrict__ hist1p,
                                              int* __restrict__ tgt,
                                              int* __restrict__ below,
                                              int* __restrict__ owner) {
    __shared__ int wsum[4];
    __shared__ int stgt[NBINS];
    __shared__ int sbelow[NBINS];
    const int c = blockIdx.x, t = threadIdx.x;
    int4 acc[4] = {make_int4(0,0,0,0), make_int4(0,0,0,0),
                   make_int4(0,0,0,0), make_int4(0,0,0,0)};
    for (int k = 0; k < B1; ++k) {
        const int4* p = (const int4*)(hist1p + ((size_t)k * NCLS + c) * 4096) + t * 4;
        #pragma unroll
        for (int j = 0; j < 4; ++j) {
            int4 v = p[j];
            acc[j].x += v.x; acc[j].y += v.y; acc[j].z += v.z; acc[j].w += v.w;
        }
    }
    int loc[16];
    #pragma unroll
    for (int j = 0; j < 4; ++j) {
        loc[j * 4 + 0] = acc[j].x; loc[j * 4 + 1] = acc[j].y;
        loc[j * 4 + 2] = acc[j].z; loc[j * 4 + 3] = acc[j].w;
    }
    int s = 0;
    #pragma unroll
    for (int i = 0; i < 16; ++i) s += loc[i];
    // block-wide exclusive prefix of per-thread totals
    const int lane = t & 63, w = t >> 6;
    int incl = s;
    #pragma unroll
    for (int d = 1; d < 64; d <<= 1) {
        int n = __shfl_up(incl, d, 64);
        if (lane >= d) incl += n;
    }
    if (lane == 63) wsum[w] = incl;
    __syncthreads();
    int woff = 0;
    #pragma unroll
    for (int j = 0; j < 4; ++j) if (j < w) woff += wsum[j];
    const int cum0 = woff + incl - s;
    for (int b = 0; b < NBINS; ++b) {
        const int f = rank_target(b);
        int cc = cum0;
        #pragma unroll
        for (int i = 0; i < 16; ++i) {
            if (f >= cc && f < cc + loc[i]) { stgt[b] = t * 16 + i; sbelow[b] = cc; }
            cc += loc[i];
        }
    }
    __syncthreads();
    if (t == 0) {
        int ow = NBINS - 1;
        for (int b = NBINS - 1; b >= 0; --b) {
            if (b == NBINS - 1 || stgt[b] != stgt[b + 1]) ow = b;   // last-of-group
            owner[c * NBINS + b] = ow;
            tgt[c * NBINS + b] = stgt[b];
            below[c * NBINS + b] = sbelow[b];
        }
    }
}

// Pass 3 (segment formulation, INT-ONLY LDS atomics): one scan produces
// (a) per-target-bucket sub-hists {n, sum v, sum v^2} (u64 fixed-point) and
// (b) equal-count segment sums {T, Q} at 2^24 fixed point in u32 slots
// seg[16][128] (slot t&127: <=2-way cross-wave sharing, conflict-free banks,
// fire-and-forget ds_add_u32).  Rounds 1-2 post-mortem: the 630us collapse was
// float-atomicAdd CAS loops (~300cy each), NOT the table gather -- hist1's
// native int atomics on the same data are fast.  All atomics here are int.
// Counts at segment boundaries come free from below[] (hist1), so the old
// min-trick (165 VALU/float4) is fully replaced by ~60 VALU + 13 LDS ops.
__global__ __launch_bounds__(256) void k_scan2(const float4* __restrict__ probsT4,
                                               const int* __restrict__ tgt,
                                               int* __restrict__ scan2p,
                                               unsigned long long* __restrict__ segG) {
    __shared__ int stg[16];
    __shared__ unsigned char tbl[4096];
    __shared__ unsigned segT[16][128];          // 8 KB
    __shared__ unsigned segQ[16][128];          // 8 KB
    __shared__ unsigned hn[HSZ];                // 3.84 KB
    __shared__ unsigned long long hT[HSZ];      // 7.68 KB
    __shared__ unsigned long long hQ[HSZ];      // 7.68 KB
    const int c = blockIdx.y, t = threadIdx.x;
    if (t < 16) stg[t] = (t < NBINS) ? tgt[c * NBINS + t] : 0x7FFFFFFF;
    for (int i = t; i < 2048; i += 256) { (&segT[0][0])[i] = 0u; (&segQ[0][0])[i] = 0u; }
    for (int i = t; i < HSZ; i += 256) { hn[i] = 0u; hT[i] = 0ull; hQ[i] = 0ull; }
    __syncthreads();                      // stg ready
    // build bucket->segment table: tbl[k] = #{b : stg[b] <= k} (upper_bound)
    {
        const int k0 = t * 16;
        int j = 0;
        j += (stg[j + 7] <= k0) ? 8 : 0;
        j += (stg[j + 3] <= k0) ? 4 : 0;
        j += (stg[j + 1] <= k0) ? 2 : 0;
        j += (stg[j] <= k0) ? 1 : 0;
        for (int k = k0; k < k0 + 16; ++k) {
            while (j < NBINS && stg[j] <= k) ++j;
            tbl[k] = (unsigned char)j;
        }
    }
    __syncthreads();                      // j-values filled
    if (t < NBINS) tbl[stg[t]] |= 0x80;   // flag target buckets (dupes idempotent)
    __syncthreads();
    const size_t base = (size_t)c * NROWS4;
    const int start = blockIdx.x * CH2;
    const int end = min(NROWS4, start + CH2);
    const int col = t & 127;
    for (int i = start + t; i < end; i += 256) {
        float4 v = probsT4[base + i];
        float val[4] = {v.x, v.y, v.z, v.w};
        unsigned bx[4] = {__float_as_uint(v.x), __float_as_uint(v.y),
                          __float_as_uint(v.z), __float_as_uint(v.w)};
        #pragma unroll
        for (int e = 0; e < 4; ++e) {
            const int k1 = (int)(bx[e] >> 18);
            const unsigned b8 = (unsigned)tbl[k1];
            const int j = (int)(b8 & 15u);
            const unsigned vT = (unsigned)fmaf(val[e], FPS, 0.5f);
            const unsigned vQ = (unsigned)fmaf(val[e] * val[e], FPS, 0.5f);
            atomicAdd(&segT[j][col], vT);            // ds_add_u32, fire-and-forget
            atomicAdd(&segQ[j][col], vQ);
            if (b8 & 0x80u) {             // inside a target bucket: sub-histogram
                int sub = (j - 1) * NSUB + (int)((bx[e] >> 12) & (NSUB - 1));
                atomicAdd(&hn[sub], 1u);
                atomicAdd(&hT[sub], (unsigned long long)vT);   // ds_add_u64
                atomicAdd(&hQ[sub], (unsigned long long)vQ);
            }
        }
    }
    __syncthreads();
    // flush private sub-hist copy: [blk*NCLS+c][3][960], T/Q converted to float
    // (same per-block-partial precision as the round-3 float path, which passed)
    int* on = scan2p + ((size_t)(blockIdx.x * NCLS + c) * 3) * HSZ;
    float* oT = (float*)(on + HSZ);
    float* oQ = (float*)(on + 2 * HSZ);
    for (int i = t; i < HSZ; i += 256) {
        on[i] = (int)hn[i];
        oT[i] = (float)((double)hT[i] * FPI);
        oQ[i] = (float)((double)hQ[i] * FPI);
    }
    // reduce seg slots (16 threads per segment, 8 slots each) -> global u64 atomics
    {
        const int j = t >> 4, p = t & 15;
        unsigned long long sT = 0ull, sQ = 0ull;
        #pragma unroll
        for (int i = 0; i < 8; ++i) {
            sT += (unsigned long long)segT[j][p * 8 + i];
            sQ += (unsigned long long)segQ[j][p * 8 + i];
        }
        #pragma unroll
        for (int o = 8; o; o >>= 1) {
            sT += __shfl_xor(sT, o, 64);
            sQ += __shfl_xor(sQ, o, 64);
        }
        if (p == 0) {
            atomicAdd(&segG[c * 32 + 2 * j], sT);
            atomicAdd(&segG[c * 32 + 2 * j + 1], sQ);
        }
    }
}

// Select sub-bucket (single wave, shfl prefix over 64 subs); cumulative {N,T,Q}
// at the boundary: cumT[b] = (sum_{j<=b} segG_T[j])*2^-24 + sub-prefix
__global__ __launch_bounds__(64) void k_sel2(const int* __restrict__ scan2p,
                                             const int* __restrict__ tgt,
                                             const int* __restrict__ below,
                                             const int* __restrict__ owner,
                                             const unsigned long long* __restrict__ segG,
                                             float* __restrict__ bounds,
                                             int* __restrict__ cumN,
                                             double* __restrict__ cumT,
                                             double* __restrict__ cumQ) {
    const int b = blockIdx.x, c = blockIdx.y, t = threadIdx.x;   // t < 64
    const int ow = owner[c * NBINS + b];
    int nj = 0; float Tj = 0.f, Qj = 0.f;
    for (int k = 0; k < B2; ++k) {
        const int* p = scan2p + ((size_t)(k * NCLS + c) * 3) * HSZ + ow * NSUB + t;
        nj += p[0];
        Tj += ((const float*)p)[HSZ];
        Qj += ((const float*)p)[2 * HSZ];
    }
    const int own = nj;
    #pragma unroll
    for (int d = 1; d < 64; d <<= 1) {
        int nn = __shfl_up(nj, d, 64);
        float TT = __shfl_up(Tj, d, 64);
        float QQ = __shfl_up(Qj, d, 64);
        if (t >= d) { nj += nn; Tj += TT; Qj += QQ; }
    }
    const int bel = below[c * NBINS + b];
    const int lr = rank_target(b) - bel;
    if (lr >= nj - own && lr < nj) {
        unsigned bits = ((unsigned)tgt[c * NBINS + b] << 18) | ((unsigned)t << 12) | 0xFFFu;
        bounds[c * NBINS + b] = __uint_as_float(bits);
        cumN[c * NBINS + b] = bel + nj;
        double A = 0.0, Qd = 0.0;
        for (int jj = 0; jj <= b; ++jj) {
            A  += (double)segG[c * 32 + 2 * jj];
            Qd += (double)segG[c * 32 + 2 * jj + 1];
        }
        cumT[c * NBINS + b] = A * FPI + (double)Tj;
        cumQ[c * NBINS + b] = Qd * FPI + (double)Qj;
    }
}

// Pass 4: label correction from the compact labConf array (coalesced), LDS-staged
// bounds + u64 fixed-point LDS accumulator (int atomics, no FP-CAS), one
// filtered global u64-atomic flush per block
__global__ __launch_bounds__(256) void k_label(const float* __restrict__ labConf,
                                               const int* __restrict__ labels,
                                               const float* __restrict__ bounds,
                                               unsigned long long* __restrict__ accLab) {
    __shared__ float sbd[NCLS * NBINS];                  // 6 KB
    __shared__ unsigned long long sacc[NCLS * NBINS * 2];// 24 KB
    const int t = threadIdx.x;
    for (int i = t; i < NCLS * NBINS; i += 256) sbd[i] = bounds[i];
    for (int i = t; i < NCLS * NBINS * 2; i += 256) sacc[i] = 0ull;
    __syncthreads();
    for (int n = blockIdx.x * 256 + t; n < NROWS; n += gridDim.x * 256) {
        const int c = labels[n];
        const float conf = labConf[n];
        const float* bd = sbd + c * NBINS;
        if (conf > bd[0]) {
            int idx = 0;
            #pragma unroll
            for (int b = 1; b < NBINS; ++b) idx += (conf > bd[b]) ? 1 : 0;
            atomicAdd(&sacc[(c * NBINS + idx) * 2 + 0], 1ull);
            atomicAdd(&sacc[(c * NBINS + idx) * 2 + 1],
                      (unsigned long long)(unsigned)fmaf(conf, FPS, 0.5f));
        }
    }
    __syncthreads();
    for (int i = t; i < NCLS * NBINS * 2; i += 256)
        if (sacc[i]) atomicAdd(&accLab[i], sacc[i]);
}

// Pass 5: closed-form LOO combine in double (totals from segment sums)
__global__ __launch_bounds__(256) void k_final(const unsigned long long* __restrict__ segG,
                                               const int* __restrict__ cumN,
                                               const double* __restrict__ cumT,
                                               const double* __restrict__ cumQ,
                                               const unsigned long long* __restrict__ accLab,
                                               float* __restrict__ out) {
    __shared__ double red[256];
    const int t = threadIdx.x;
    double local = 0.0;
    for (int k = t; k < NCLS * NBINS; k += 256) {
        int c = k / NBINS, b = k - c * NBINS;
        double n, T, Q;
        if (b < NBINS - 1) {
            n = (double)(cumN[k + 1] - cumN[k]);
            T = cumT[k + 1] - cumT[k];
            Q = cumQ[k + 1] - cumQ[k];
        } else {
            unsigned long long uT = 0ull, uQ = 0ull;
            for (int j = 0; j < 16; ++j) {
                uT += segG[c * 32 + 2 * j];
                uQ += segG[c * 32 + 2 * j + 1];
            }
            n = (double)(NROWS - cumN[k]);
            T = (double)uT * FPI - cumT[k];
            Q = (double)uQ * FPI - cumQ[k];
        }
        double S = (double)accLab[k * 2 + 0];
        double T1 = (double)accLab[k * 2 + 1] * FPI;
        if (n > 1.5) {
            double inv = 1.0 / (n - 1.0);
            double a0 = S * inv, a1 = (S - 1.0) * inv;
            local += Q - 2.0 * a0 * T + 2.0 * T1 * inv + (n - S) * a0 * a0 + S * a1 * a1;
        }
    }
    red[t] = local;
    __syncthreads();
    for (int s = 128; s; s >>= 1) {
        if (t < s) red[t] += red[t + s];
        __syncthreads();
    }
    if (t == 0) out[0] = (float)(red[0] / ((double)NROWS * (double)NCLS));
}

extern "C" void kernel_launch(void* const* d_in, const int* in_sizes, int n_in,
                              void* d_out, int out_size, void* d_ws, size_t ws_size,
                              hipStream_t stream) {
    const float* logits = (const float*)d_in[0];
    const int* labels = (const int*)d_in[1];
    float* out = (float*)d_out;
    char* ws = (char*)d_ws;
    size_t off = 0;
    auto alloc = [&](size_t bytes) -> void* {
        off = (off + 255) & ~(size_t)255;
        void* p = ws + off;
        off += bytes;
        return p;
    };
    float* probsT = (float*)alloc((size_t)NCLS * NROWS * 4);               // 200 MB
    // shared region: hist1p (hist1->sel1) then reused as scan2p (scan2->sel2)
    size_t h1bytes = (size_t)B1 * NCLS * 4096 * 4;                         // 22.9 MB
    size_t s2bytes = (size_t)B2 * NCLS * 3 * HSZ * 4;                      // 32.3 MB
    int* hist1p = (int*)alloc(h1bytes > s2bytes ? h1bytes : s2bytes);
    int* scan2p = hist1p;
    float* labConf = (float*)alloc((size_t)NROWS * 4);                     // 2 MB
    // --- zeroed region (contiguous, single small memset) ---
    char* zbase = ws + ((off + 255) & ~(size_t)255);
    unsigned long long* segG   = (unsigned long long*)alloc((size_t)NCLS * 32 * 8);
    unsigned long long* accLab = (unsigned long long*)alloc((size_t)NCLS * NBINS * 2 * 8);
    size_t zlen = (size_t)((ws + off) - zbase);
    // --- written-before-read region ---
    int*    tgt     = (int*)alloc((size_t)NCLS * NBINS * 4);
    int*    below   = (int*)alloc((size_t)NCLS * NBINS * 4);
    int*    owner   = (int*)alloc((size_t)NCLS * NBINS * 4);
    float*  bounds  = (float*)alloc((size_t)NCLS * NBINS * 4);
    int*    cumN    = (int*)alloc((size_t)NCLS * NBINS * 4);
    double* cumT    = (double*)alloc((size_t)NCLS * NBINS * 8);
    double* cumQ    = (double*)alloc((size_t)NCLS * NBINS * 8);
    if (off > ws_size) {
        hipMemsetAsync(d_out, 0xFF, 4, stream);   // NaN sentinel
        return;
    }
    hipMemsetAsync(zbase, 0, zlen, stream);

    k_softmax_t<<<(NROWS + 63) / 64, 256, 0, stream>>>(logits, labels, probsT, labConf);
    k_hist1<<<dim3(B1, NCLS), 256, 0, stream>>>((const float4*)probsT, hist1p);
    k_sel1<<<NCLS, 256, 0, stream>>>(hist1p, tgt, below, owner);
    k_scan2<<<dim3(B2, NCLS), 256, 0, stream>>>((const float4*)probsT, tgt, scan2p, segG);
    k_sel2<<<dim3(NBINS, NCLS), 64, 0, stream>>>(scan2p, tgt, below, owner, segG,
                                                 bounds, cumN, cumT, cumQ);
    k_label<<<128, 256, 0, stream>>>(labConf, labels, bounds, accLab);
    k_final<<<1, 256, 0, stream>>>(segG, cumN, cumT, cumQ, accLab, out);
}

// Round 5
// 475.214 us; speedup vs baseline: 2.1887x; 1.0059x over previous
//
#include <hip/hip_runtime.h>
#include <stdint.h>

#define NROWS 500000
#define NROWS4 125000
#define NCLS 100
#define NBINS 15
#define NSUB 64          // sub-bucket = 4096 ULP; ~70 elems/sub near mode -> rank err << tolerance
#define B1 14
#define CH1 8929         // ceil(125000/14) float4s per hist1 block
#define B2 28
#define CH2 4465         // ceil(125000/28) float4s per scan2 block
#define HSZ (NBINS * NSUB)   // 960
#define FPS 16777216.0f      // 2^24 fixed-point scale (u32 slot: 144 elems * 2^24 = 2.4e9 < 4.3e9)
#define FPI (1.0 / 16777216.0)

__device__ __forceinline__ int rank_target(int b) {
    if (b == 0) return 0;
    const float step = 500000.0f / 15.0f;   // float32-rounded, mimics jnp.linspace
    return (int)floorf((float)b * step);
}

// Pass 1: row softmax of logits [N][C], write transposed probsT [C][N].
// Round-5 restructure: float4 global loads (25 scalar VMEM + k/100 div per
// thread -> 7 vector VMEM + k/25), and the 4-threads-per-row max/sum combine
// done with ordered 3-shfl reads inside the wave (the 4 row-threads are
// adjacent lanes) instead of two LDS reduction round-trips: 5 syncthreads -> 2.
// Summation order ((s0+s1)+s2)+s3 preserved exactly -> bit-identical probs.
// Also emits labConf[n] = prob of the labeled class (bit-identical product to
// the stored probsT value), so k_label never has to gather probsT.
__global__ __launch_bounds__(256) void k_softmax_t(const float4* __restrict__ logits4,
                                                   const int* __restrict__ labels,
                                                   float* __restrict__ probsT,
                                                   float* __restrict__ labConf) {
    __shared__ float tile[64][101];   // 101 pad: store-phase reads land 2-way max
    __shared__ float inv[64];
    const int row0 = blockIdx.x * 64;
    const int rows = min(64, NROWS - row0);
    const int t = threadIdx.x;
    // load: rows*25 float4s, coalesced
    const float4* lg4 = logits4 + (size_t)row0 * 25;
    const int total4 = rows * 25;
    for (int k = t; k < total4; k += 256) {
        float4 v = lg4[k];
        int r = k / 25, c4 = (k - r * 25) * 4;
        tile[r][c4 + 0] = v.x; tile[r][c4 + 1] = v.y;
        tile[r][c4 + 2] = v.z; tile[r][c4 + 3] = v.w;
    }
    __syncthreads();
    const int r = t >> 2, q = t & 3;   // 4 adjacent lanes per row
    if (r < rows) {
        float m = -1e30f;
        #pragma unroll
        for (int c = 0; c < 25; ++c) m = fmaxf(m, tile[r][q * 25 + c]);
        const int lb = t & ~3;         // lane group base (mod-64 applied by shfl)
        float m0 = __shfl(m, lb + 0, 64), m1 = __shfl(m, lb + 1, 64);
        float m2 = __shfl(m, lb + 2, 64), m3 = __shfl(m, lb + 3, 64);
        m = fmaxf(fmaxf(m0, m1), fmaxf(m2, m3));          // same as old mx[r]
        float s = 0.f;
        #pragma unroll
        for (int c = 0; c < 25; ++c) {
            float e = __expf(tile[r][q * 25 + c] - m);
            tile[r][q * 25 + c] = e;
            s += e;
        }
        float s0 = __shfl(s, lb + 0, 64), s1 = __shfl(s, lb + 1, 64);
        float s2 = __shfl(s, lb + 2, 64), s3 = __shfl(s, lb + 3, 64);
        if (q == 0) inv[r] = 1.0f / (((s0 + s1) + s2) + s3);   // exact old order
    }
    __syncthreads();
    if (t < rows) {
        const int lab = labels[row0 + t];
        labConf[row0 + t] = tile[t][lab] * inv[t];   // same product as probsT store
    }
    const int shift = (rows == 64) ? 4 : 3;
    const int gq = 1 << shift;
    const int ng = NCLS << shift;
    for (int k = t; k < ng; k += 256) {
        int c = k >> shift, g = k & (gq - 1);
        int rr = g << 2;
        float4 o;
        o.x = tile[rr + 0][c] * inv[rr + 0];
        o.y = tile[rr + 1][c] * inv[rr + 1];
        o.z = tile[rr + 2][c] * inv[rr + 2];
        o.w = tile[rr + 3][c] * inv[rr + 3];
        *(float4*)(probsT + (size_t)c * NROWS + row0 + rr) = o;
    }
}

// Pass 2: per-class L1 histogram (top 12 used float bits), 2 bank-rotated LDS
// copies, non-atomic flush to private copy per blockIdx.x.  Int atomics only
// (ds_add_u32 native; this kernel was never a problem).
__global__ __launch_bounds__(256) void k_hist1(const float4* __restrict__ probsT4,
                                               int* __restrict__ hist1p) {
    __shared__ int h[2][4096];   // 32 KB
    const int c = blockIdx.y, t = threadIdx.x;
    int4* hz = (int4*)&h[0][0];
    for (int i = t; i < 2048; i += 256) hz[i] = make_int4(0, 0, 0, 0);
    __syncthreads();
    const int copy = t & 1;
    const int rot = copy << 4;
    const size_t base = (size_t)c * NROWS4;
    const int start = blockIdx.x * CH1;
    const int end = min(NROWS4, start + CH1);
    for (int i = start + t; i < end; i += 256) {
        float4 v = probsT4[base + i];
        atomicAdd(&h[copy][((__float_as_uint(v.x) >> 18) + rot) & 4095], 1);
        atomicAdd(&h[copy][((__float_as_uint(v.y) >> 18) + rot) & 4095], 1);
        atomicAdd(&h[copy][((__float_as_uint(v.z) >> 18) + rot) & 4095], 1);
        atomicAdd(&h[copy][((__float_as_uint(v.w) >> 18) + rot) & 4095], 1);
    }
    __syncthreads();
    int* out = hist1p + ((size_t)blockIdx.x * NCLS + c) * 4096;
    for (int i = t; i < 4096; i += 256)
        out[i] = h[0][i] + h[1][(i + 16) & 4095];
}

// Select L1 bucket per rank target; parallel prefix (shfl), dedupe via owner[]
// (owner = LAST slot of a duplicate-target group, matching scan2's upper_bound
// table semantics; this pairing passed exact in rounds 1-2 and 4)
__global__ __launch_bounds__(256) void k_sel1(const int* __restrict__ hist1p,
                                              int* __restrict__ tgt,
                                              int* __restrict__ below,
                                              int* __restrict__ owner) {
    __shared__ int wsum[4];
    __shared__ int stgt[NBINS];
    __shared__ int sbelow[NBINS];
    const int c = blockIdx.x, t = threadIdx.x;
    int4 acc[4] = {make_int4(0,0,0,0), make_int4(0,0,0,0),
                   make_int4(0,0,0,0), make_int4(0,0,0,0)};
    for (int k = 0; k < B1; ++k) {
        const int4* p = (const int4*)(hist1p + ((size_t)k * NCLS + c) * 4096) + t * 4;
        #pragma unroll
        for (int j = 0; j < 4; ++j) {
            int4 v = p[j];
            acc[j].x += v.x; acc[j].y += v.y; acc[j].z += v.z; acc[j].w += v.w;
        }
    }
    int loc[16];
    #pragma unroll
    for (int j = 0; j < 4; ++j) {
        loc[j * 4 + 0] = acc[j].x; loc[j * 4 + 1] = acc[j].y;
        loc[j * 4 + 2] = acc[j].z; loc[j * 4 + 3] = acc[j].w;
    }
    int s = 0;
    #pragma unroll
    for (int i = 0; i < 16; ++i) s += loc[i];
    // block-wide exclusive prefix of per-thread totals
    const int lane = t & 63, w = t >> 6;
    int incl = s;
    #pragma unroll
    for (int d = 1; d < 64; d <<= 1) {
        int n = __shfl_up(incl, d, 64);
        if (lane >= d) incl += n;
    }
    if (lane == 63) wsum[w] = incl;
    __syncthreads();
    int woff = 0;
    #pragma unroll
    for (int j = 0; j < 4; ++j) if (j < w) woff += wsum[j];
    const int cum0 = woff + incl - s;
    for (int b = 0; b < NBINS; ++b) {
        const int f = rank_target(b);
        int cc = cum0;
        #pragma unroll
        for (int i = 0; i < 16; ++i) {
            if (f >= cc && f < cc + loc[i]) { stgt[b] = t * 16 + i; sbelow[b] = cc; }
            cc += loc[i];
        }
    }
    __syncthreads();
    if (t == 0) {
        int ow = NBINS - 1;
        for (int b = NBINS - 1; b >= 0; --b) {
            if (b == NBINS - 1 || stgt[b] != stgt[b + 1]) ow = b;   // last-of-group
            owner[c * NBINS + b] = ow;
            tgt[c * NBINS + b] = stgt[b];
            below[c * NBINS + b] = sbelow[b];
        }
    }
}

// Pass 3 (segment formulation, INT-ONLY LDS atomics): one scan produces
// (a) per-target-bucket sub-hists {n, sum v, sum v^2} (u64 fixed-point) and
// (b) equal-count segment sums {T, Q} at 2^24 fixed point in u32 slots
// seg[16][128] (slot t&127: <=2-way cross-wave sharing, conflict-free banks,
// fire-and-forget ds_add_u32).  Rounds 1-2 post-mortem: the 630us collapse was
// float-atomicAdd CAS loops (~300cy each), NOT the table gather -- hist1's
// native int atomics on the same data are fast.  All atomics here are int.
__global__ __launch_bounds__(256) void k_scan2(const float4* __restrict__ probsT4,
                                               const int* __restrict__ tgt,
                                               int* __restrict__ scan2p,
                                               unsigned long long* __restrict__ segG) {
    __shared__ int stg[16];
    __shared__ unsigned char tbl[4096];
    __shared__ unsigned segT[16][128];          // 8 KB
    __shared__ unsigned segQ[16][128];          // 8 KB
    __shared__ unsigned hn[HSZ];                // 3.84 KB
    __shared__ unsigned long long hT[HSZ];      // 7.68 KB
    __shared__ unsigned long long hQ[HSZ];      // 7.68 KB
    const int c = blockIdx.y, t = threadIdx.x;
    if (t < 16) stg[t] = (t < NBINS) ? tgt[c * NBINS + t] : 0x7FFFFFFF;
    for (int i = t; i < 2048; i += 256) { (&segT[0][0])[i] = 0u; (&segQ[0][0])[i] = 0u; }
    for (int i = t; i < HSZ; i += 256) { hn[i] = 0u; hT[i] = 0ull; hQ[i] = 0ull; }
    __syncthreads();                      // stg ready
    // build bucket->segment table: tbl[k] = #{b : stg[b] <= k} (upper_bound)
    {
        const int k0 = t * 16;
        int j = 0;
        j += (stg[j + 7] <= k0) ? 8 : 0;
        j += (stg[j + 3] <= k0) ? 4 : 0;
        j += (stg[j + 1] <= k0) ? 2 : 0;
        j += (stg[j] <= k0) ? 1 : 0;
        for (int k = k0; k < k0 + 16; ++k) {
            while (j < NBINS && stg[j] <= k) ++j;
            tbl[k] = (unsigned char)j;
        }
    }
    __syncthreads();                      // j-values filled
    if (t < NBINS) tbl[stg[t]] |= 0x80;   // flag target buckets (dupes idempotent)
    __syncthreads();
    const size_t base = (size_t)c * NROWS4;
    const int start = blockIdx.x * CH2;
    const int end = min(NROWS4, start + CH2);
    const int col = t & 127;
    for (int i = start + t; i < end; i += 256) {
        float4 v = probsT4[base + i];
        float val[4] = {v.x, v.y, v.z, v.w};
        unsigned bx[4] = {__float_as_uint(v.x), __float_as_uint(v.y),
                          __float_as_uint(v.z), __float_as_uint(v.w)};
        #pragma unroll
        for (int e = 0; e < 4; ++e) {
            const int k1 = (int)(bx[e] >> 18);
            const unsigned b8 = (unsigned)tbl[k1];
            const int j = (int)(b8 & 15u);
            const unsigned vT = (unsigned)fmaf(val[e], FPS, 0.5f);
            const unsigned vQ = (unsigned)fmaf(val[e] * val[e], FPS, 0.5f);
            atomicAdd(&segT[j][col], vT);            // ds_add_u32, fire-and-forget
            atomicAdd(&segQ[j][col], vQ);
            if (b8 & 0x80u) {             // inside a target bucket: sub-histogram
                int sub = (j - 1) * NSUB + (int)((bx[e] >> 12) & (NSUB - 1));
                atomicAdd(&hn[sub], 1u);
                atomicAdd(&hT[sub], (unsigned long long)vT);   // ds_add_u64
                atomicAdd(&hQ[sub], (unsigned long long)vQ);
            }
        }
    }
    __syncthreads();
    // flush private sub-hist copy: [blk*NCLS+c][3][960], T/Q converted to float
    int* on = scan2p + ((size_t)(blockIdx.x * NCLS + c) * 3) * HSZ;
    float* oT = (float*)(on + HSZ);
    float* oQ = (float*)(on + 2 * HSZ);
    for (int i = t; i < HSZ; i += 256) {
        on[i] = (int)hn[i];
        oT[i] = (float)((double)hT[i] * FPI);
        oQ[i] = (float)((double)hQ[i] * FPI);
    }
    // reduce seg slots (16 threads per segment, 8 slots each) -> global u64 atomics
    {
        const int j = t >> 4, p = t & 15;
        unsigned long long sT = 0ull, sQ = 0ull;
        #pragma unroll
        for (int i = 0; i < 8; ++i) {
            sT += (unsigned long long)segT[j][p * 8 + i];
            sQ += (unsigned long long)segQ[j][p * 8 + i];
        }
        #pragma unroll
        for (int o = 8; o; o >>= 1) {
            sT += __shfl_xor(sT, o, 64);
            sQ += __shfl_xor(sQ, o, 64);
        }
        if (p == 0) {
            atomicAdd(&segG[c * 32 + 2 * j], sT);
            atomicAdd(&segG[c * 32 + 2 * j + 1], sQ);
        }
    }
}

// Select sub-bucket (single wave, shfl prefix over 64 subs); cumulative {N,T,Q}
// at the boundary: cumT[b] = (sum_{j<=b} segG_T[j])*2^-24 + sub-prefix
__global__ __launch_bounds__(64) void k_sel2(const int* __restrict__ scan2p,
                                             const int* __restrict__ tgt,
                                             const int* __restrict__ below,
                                             const int* __restrict__ owner,
                                             const unsigned long long* __restrict__ segG,
                                             float* __restrict__ bounds,
                                             int* __restrict__ cumN,
                                             double* __restrict__ cumT,
                                             double* __restrict__ cumQ) {
    const int b = blockIdx.x, c = blockIdx.y, t = threadIdx.x;   // t < 64
    const int ow = owner[c * NBINS + b];
    int nj = 0; float Tj = 0.f, Qj = 0.f;
    for (int k = 0; k < B2; ++k) {
        const int* p = scan2p + ((size_t)(k * NCLS + c) * 3) * HSZ + ow * NSUB + t;
        nj += p[0];
        Tj += ((const float*)p)[HSZ];
        Qj += ((const float*)p)[2 * HSZ];
    }
    const int own = nj;
    #pragma unroll
    for (int d = 1; d < 64; d <<= 1) {
        int nn = __shfl_up(nj, d, 64);
        float TT = __shfl_up(Tj, d, 64);
        float QQ = __shfl_up(Qj, d, 64);
        if (t >= d) { nj += nn; Tj += TT; Qj += QQ; }
    }
    const int bel = below[c * NBINS + b];
    const int lr = rank_target(b) - bel;
    if (lr >= nj - own && lr < nj) {
        unsigned bits = ((unsigned)tgt[c * NBINS + b] << 18) | ((unsigned)t << 12) | 0xFFFu;
        bounds[c * NBINS + b] = __uint_as_float(bits);
        cumN[c * NBINS + b] = bel + nj;
        double A = 0.0, Qd = 0.0;
        for (int jj = 0; jj <= b; ++jj) {
            A  += (double)segG[c * 32 + 2 * jj];
            Qd += (double)segG[c * 32 + 2 * jj + 1];
        }
        cumT[c * NBINS + b] = A * FPI + (double)Tj;
        cumQ[c * NBINS + b] = Qd * FPI + (double)Qj;
    }
}

// Pass 4: label correction from the compact labConf array (coalesced), LDS-staged
// bounds + u64 fixed-point LDS accumulator (int atomics, no FP-CAS), one
// filtered global u64-atomic flush per block
__global__ __launch_bounds__(256) void k_label(const float* __restrict__ labConf,
                                               const int* __restrict__ labels,
                                               const float* __restrict__ bounds,
                                               unsigned long long* __restrict__ accLab) {
    __shared__ float sbd[NCLS * NBINS];                  // 6 KB
    __shared__ unsigned long long sacc[NCLS * NBINS * 2];// 24 KB
    const int t = threadIdx.x;
    for (int i = t; i < NCLS * NBINS; i += 256) sbd[i] = bounds[i];
    for (int i = t; i < NCLS * NBINS * 2; i += 256) sacc[i] = 0ull;
    __syncthreads();
    for (int n = blockIdx.x * 256 + t; n < NROWS; n += gridDim.x * 256) {
        const int c = labels[n];
        const float conf = labConf[n];
        const float* bd = sbd + c * NBINS;
        if (conf > bd[0]) {
            int idx = 0;
            #pragma unroll
            for (int b = 1; b < NBINS; ++b) idx += (conf > bd[b]) ? 1 : 0;
            atomicAdd(&sacc[(c * NBINS + idx) * 2 + 0], 1ull);
            atomicAdd(&sacc[(c * NBINS + idx) * 2 + 1],
                      (unsigned long long)(unsigned)fmaf(conf, FPS, 0.5f));
        }
    }
    __syncthreads();
    for (int i = t; i < NCLS * NBINS * 2; i += 256)
        if (sacc[i]) atomicAdd(&accLab[i], sacc[i]);
}

// Pass 5: closed-form LOO combine in double (totals from segment sums)
__global__ __launch_bounds__(256) void k_final(const unsigned long long* __restrict__ segG,
                                               const int* __restrict__ cumN,
                                               const double* __restrict__ cumT,
                                               const double* __restrict__ cumQ,
                                               const unsigned long long* __restrict__ accLab,
                                               float* __restrict__ out) {
    __shared__ double red[256];
    const int t = threadIdx.x;
    double local = 0.0;
    for (int k = t; k < NCLS * NBINS; k += 256) {
        int c = k / NBINS, b = k - c * NBINS;
        double n, T, Q;
        if (b < NBINS - 1) {
            n = (double)(cumN[k + 1] - cumN[k]);
            T = cumT[k + 1] - cumT[k];
            Q = cumQ[k + 1] - cumQ[k];
        } else {
            unsigned long long uT = 0ull, uQ = 0ull;
            for (int j = 0; j < 16; ++j) {
                uT += segG[c * 32 + 2 * j];
                uQ += segG[c * 32 + 2 * j + 1];
            }
            n = (double)(NROWS - cumN[k]);
            T = (double)uT * FPI - cumT[k];
            Q = (double)uQ * FPI - cumQ[k];
        }
        double S = (double)accLab[k * 2 + 0];
        double T1 = (double)accLab[k * 2 + 1] * FPI;
        if (n > 1.5) {
            double inv = 1.0 / (n - 1.0);
            double a0 = S * inv, a1 = (S - 1.0) * inv;
            local += Q - 2.0 * a0 * T + 2.0 * T1 * inv + (n - S) * a0 * a0 + S * a1 * a1;
        }
    }
    red[t] = local;
    __syncthreads();
    for (int s = 128; s; s >>= 1) {
        if (t < s) red[t] += red[t + s];
        __syncthreads();
    }
    if (t == 0) out[0] = (float)(red[0] / ((double)NROWS * (double)NCLS));
}

extern "C" void kernel_launch(void* const* d_in, const int* in_sizes, int n_in,
                              void* d_out, int out_size, void* d_ws, size_t ws_size,
                              hipStream_t stream) {
    const float* logits = (const float*)d_in[0];
    const int* labels = (const int*)d_in[1];
    float* out = (float*)d_out;
    char* ws = (char*)d_ws;
    size_t off = 0;
    auto alloc = [&](size_t bytes) -> void* {
        off = (off + 255) & ~(size_t)255;
        void* p = ws + off;
        off += bytes;
        return p;
    };
    float* probsT = (float*)alloc((size_t)NCLS * NROWS * 4);               // 200 MB
    // shared region: hist1p (hist1->sel1) then reused as scan2p (scan2->sel2)
    size_t h1bytes = (size_t)B1 * NCLS * 4096 * 4;                         // 22.9 MB
    size_t s2bytes = (size_t)B2 * NCLS * 3 * HSZ * 4;                      // 32.3 MB
    int* hist1p = (int*)alloc(h1bytes > s2bytes ? h1bytes : s2bytes);
    int* scan2p = hist1p;
    float* labConf = (float*)alloc((size_t)NROWS * 4);                     // 2 MB
    // --- zeroed region (contiguous, single small memset) ---
    char* zbase = ws + ((off + 255) & ~(size_t)255);
    unsigned long long* segG   = (unsigned long long*)alloc((size_t)NCLS * 32 * 8);
    unsigned long long* accLab = (unsigned long long*)alloc((size_t)NCLS * NBINS * 2 * 8);
    size_t zlen = (size_t)((ws + off) - zbase);
    // --- written-before-read region ---
    int*    tgt     = (int*)alloc((size_t)NCLS * NBINS * 4);
    int*    below   = (int*)alloc((size_t)NCLS * NBINS * 4);
    int*    owner   = (int*)alloc((size_t)NCLS * NBINS * 4);
    float*  bounds  = (float*)alloc((size_t)NCLS * NBINS * 4);
    int*    cumN    = (int*)alloc((size_t)NCLS * NBINS * 4);
    double* cumT    = (double*)alloc((size_t)NCLS * NBINS * 8);
    double* cumQ    = (double*)alloc((size_t)NCLS * NBINS * 8);
    if (off > ws_size) {
        hipMemsetAsync(d_out, 0xFF, 4, stream);   // NaN sentinel
        return;
    }
    hipMemsetAsync(zbase, 0, zlen, stream);

    k_softmax_t<<<(NROWS + 63) / 64, 256, 0, stream>>>((const float4*)logits, labels,
                                                       probsT, labConf);
    k_hist1<<<dim3(B1, NCLS), 256, 0, stream>>>((const float4*)probsT, hist1p);
    k_sel1<<<NCLS, 256, 0, stream>>>(hist1p, tgt, below, owner);
    k_scan2<<<dim3(B2, NCLS), 256, 0, stream>>>((const float4*)probsT, tgt, scan2p, segG);
    k_sel2<<<dim3(NBINS, NCLS), 64, 0, stream>>>(scan2p, tgt, below, owner, segG,
                                                 bounds, cumN, cumT, cumQ);
    k_label<<<128, 256, 0, stream>>>(labConf, labels, bounds, accLab);
    k_final<<<1, 256, 0, stream>>>(segG, cumN, cumT, cumQ, accLab, out);
}

// Round 6
// 471.547 us; speedup vs baseline: 2.2057x; 1.0078x over previous
//
#include <hip/hip_runtime.h>
#include <stdint.h>

#define NROWS 500000
#define NROWS4 125000
#define NCLS 100
#define NBINS 15
#define NSUB 64          // sub-bucket = 4096 ULP; ~70 elems/sub near mode -> rank err << tolerance
#define B1 14
#define CH1 8929         // ceil(125000/14) float4s per hist1 block
#define B2 28
#define CH2 4465         // ceil(125000/28) float4s per scan2 block
#define HSZ (NBINS * NSUB)   // 960
#define FPS 16777216.0f      // 2^24 fixed-point scale (u32 slot: 144 elems * 2^24 = 2.4e9 < 4.3e9)
#define FPI (1.0 / 16777216.0)

__device__ __forceinline__ int rank_target(int b) {
    if (b == 0) return 0;
    const float step = 500000.0f / 15.0f;   // float32-rounded, mimics jnp.linspace
    return (int)floorf((float)b * step);
}

// Pass 1: row softmax of logits [N][C], write transposed probsT [C][N].
// float4 loads, 4-adjacent-lane shfl reduction (exact old summation order ->
// bit-identical probs), 2 syncthreads.  Emits labConf[n] = prob of labeled
// class so k_label never gathers probsT.  (Round-5 lesson: this kernel is
// HBM-traffic-bound, ~400MB; further issue-side tuning is pointless.)
__global__ __launch_bounds__(256) void k_softmax_t(const float4* __restrict__ logits4,
                                                   const int* __restrict__ labels,
                                                   float* __restrict__ probsT,
                                                   float* __restrict__ labConf) {
    __shared__ float tile[64][101];
    __shared__ float inv[64];
    const int row0 = blockIdx.x * 64;
    const int rows = min(64, NROWS - row0);
    const int t = threadIdx.x;
    const float4* lg4 = logits4 + (size_t)row0 * 25;
    const int total4 = rows * 25;
    for (int k = t; k < total4; k += 256) {
        float4 v = lg4[k];
        int r = k / 25, c4 = (k - r * 25) * 4;
        tile[r][c4 + 0] = v.x; tile[r][c4 + 1] = v.y;
        tile[r][c4 + 2] = v.z; tile[r][c4 + 3] = v.w;
    }
    __syncthreads();
    const int r = t >> 2, q = t & 3;   // 4 adjacent lanes per row
    if (r < rows) {
        float m = -1e30f;
        #pragma unroll
        for (int c = 0; c < 25; ++c) m = fmaxf(m, tile[r][q * 25 + c]);
        const int lb = t & ~3;
        float m0 = __shfl(m, lb + 0, 64), m1 = __shfl(m, lb + 1, 64);
        float m2 = __shfl(m, lb + 2, 64), m3 = __shfl(m, lb + 3, 64);
        m = fmaxf(fmaxf(m0, m1), fmaxf(m2, m3));
        float s = 0.f;
        #pragma unroll
        for (int c = 0; c < 25; ++c) {
            float e = __expf(tile[r][q * 25 + c] - m);
            tile[r][q * 25 + c] = e;
            s += e;
        }
        float s0 = __shfl(s, lb + 0, 64), s1 = __shfl(s, lb + 1, 64);
        float s2 = __shfl(s, lb + 2, 64), s3 = __shfl(s, lb + 3, 64);
        if (q == 0) inv[r] = 1.0f / (((s0 + s1) + s2) + s3);
    }
    __syncthreads();
    if (t < rows) {
        const int lab = labels[row0 + t];
        labConf[row0 + t] = tile[t][lab] * inv[t];
    }
    const int shift = (rows == 64) ? 4 : 3;
    const int gq = 1 << shift;
    const int ng = NCLS << shift;
    for (int k = t; k < ng; k += 256) {
        int c = k >> shift, g = k & (gq - 1);
        int rr = g << 2;
        float4 o;
        o.x = tile[rr + 0][c] * inv[rr + 0];
        o.y = tile[rr + 1][c] * inv[rr + 1];
        o.z = tile[rr + 2][c] * inv[rr + 2];
        o.w = tile[rr + 3][c] * inv[rr + 3];
        *(float4*)(probsT + (size_t)c * NROWS + row0 + rr) = o;
    }
}

// Pass 2: per-class L1 histogram.  Round-6: 4x load-unroll -- one load per
// iter x 5 resident blocks/CU gave only ~5 outstanding loads/SIMD against
// ~900cy HBM latency (latency-bound).  4 back-to-back independent float4
// loads per thread -> 20 outstanding/SIMD.
__global__ __launch_bounds__(256) void k_hist1(const float4* __restrict__ probsT4,
                                               int* __restrict__ hist1p) {
    __shared__ int h[2][4096];   // 32 KB
    const int c = blockIdx.y, t = threadIdx.x;
    int4* hz = (int4*)&h[0][0];
    for (int i = t; i < 2048; i += 256) hz[i] = make_int4(0, 0, 0, 0);
    __syncthreads();
    const int copy = t & 1;
    const int rot = copy << 4;
    const size_t base = (size_t)c * NROWS4;
    const int start = blockIdx.x * CH1;
    const int end = min(NROWS4, start + CH1);
    auto proc = [&](float4 v) {
        atomicAdd(&h[copy][((__float_as_uint(v.x) >> 18) + rot) & 4095], 1);
        atomicAdd(&h[copy][((__float_as_uint(v.y) >> 18) + rot) & 4095], 1);
        atomicAdd(&h[copy][((__float_as_uint(v.z) >> 18) + rot) & 4095], 1);
        atomicAdd(&h[copy][((__float_as_uint(v.w) >> 18) + rot) & 4095], 1);
    };
    int i = start + t;
    for (; i + 768 < end; i += 1024) {
        float4 w0 = probsT4[base + i];
        float4 w1 = probsT4[base + i + 256];
        float4 w2 = probsT4[base + i + 512];
        float4 w3 = probsT4[base + i + 768];
        proc(w0); proc(w1); proc(w2); proc(w3);
    }
    for (; i < end; i += 256) proc(probsT4[base + i]);
    __syncthreads();
    int* out = hist1p + ((size_t)blockIdx.x * NCLS + c) * 4096;
    for (int i2 = t; i2 < 4096; i2 += 256)
        out[i2] = h[0][i2] + h[1][(i2 + 16) & 4095];
}

// Select L1 bucket per rank target; parallel prefix (shfl), dedupe via owner[]
// (owner = LAST slot of a duplicate-target group, matching scan2's upper_bound
// table semantics; this pairing passed exact in rounds 1-2 and 4-5)
__global__ __launch_bounds__(256) void k_sel1(const int* __restrict__ hist1p,
                                              int* __restrict__ tgt,
                                              int* __restrict__ below,
                                              int* __restrict__ owner) {
    __shared__ int wsum[4];
    __shared__ int stgt[NBINS];
    __shared__ int sbelow[NBINS];
    const int c = blockIdx.x, t = threadIdx.x;
    int4 acc[4] = {make_int4(0,0,0,0), make_int4(0,0,0,0),
                   make_int4(0,0,0,0), make_int4(0,0,0,0)};
    for (int k = 0; k < B1; ++k) {
        const int4* p = (const int4*)(hist1p + ((size_t)k * NCLS + c) * 4096) + t * 4;
        #pragma unroll
        for (int j = 0; j < 4; ++j) {
            int4 v = p[j];
            acc[j].x += v.x; acc[j].y += v.y; acc[j].z += v.z; acc[j].w += v.w;
        }
    }
    int loc[16];
    #pragma unroll
    for (int j = 0; j < 4; ++j) {
        loc[j * 4 + 0] = acc[j].x; loc[j * 4 + 1] = acc[j].y;
        loc[j * 4 + 2] = acc[j].z; loc[j * 4 + 3] = acc[j].w;
    }
    int s = 0;
    #pragma unroll
    for (int i = 0; i < 16; ++i) s += loc[i];
    // block-wide exclusive prefix of per-thread totals
    const int lane = t & 63, w = t >> 6;
    int incl = s;
    #pragma unroll
    for (int d = 1; d < 64; d <<= 1) {
        int n = __shfl_up(incl, d, 64);
        if (lane >= d) incl += n;
    }
    if (lane == 63) wsum[w] = incl;
    __syncthreads();
    int woff = 0;
    #pragma unroll
    for (int j = 0; j < 4; ++j) if (j < w) woff += wsum[j];
    const int cum0 = woff + incl - s;
    for (int b = 0; b < NBINS; ++b) {
        const int f = rank_target(b);
        int cc = cum0;
        #pragma unroll
        for (int i = 0; i < 16; ++i) {
            if (f >= cc && f < cc + loc[i]) { stgt[b] = t * 16 + i; sbelow[b] = cc; }
            cc += loc[i];
        }
    }
    __syncthreads();
    if (t == 0) {
        int ow = NBINS - 1;
        for (int b = NBINS - 1; b >= 0; --b) {
            if (b == NBINS - 1 || stgt[b] != stgt[b + 1]) ow = b;   // last-of-group
            owner[c * NBINS + b] = ow;
            tgt[c * NBINS + b] = stgt[b];
            below[c * NBINS + b] = sbelow[b];
        }
    }
}

// Pass 3 (segment formulation, INT-ONLY LDS atomics, 4x load-unroll): one scan
// produces (a) per-target-bucket sub-hists {n, sum v, sum v^2} (u64 fixed-pt)
// and (b) equal-count segment sums {T, Q} at 2^24 fixed point in u32 slots
// seg[16][128] (slot t&127: no intra-wave same-address, conflict-free banks,
// fire-and-forget ds_add_u32).  Round-5 arithmetic: issue cost is ~8us/SIMD,
// so 73us was latency-bound (4 blocks/CU from 40KB LDS x 1 load/iter = 4
// outstanding/SIMD).  4-unroll -> 16 outstanding/SIMD.
__global__ __launch_bounds__(256) void k_scan2(const float4* __restrict__ probsT4,
                                               const int* __restrict__ tgt,
                                               int* __restrict__ scan2p,
                                               unsigned long long* __restrict__ segG) {
    __shared__ int stg[16];
    __shared__ unsigned char tbl[4096];
    __shared__ unsigned segT[16][128];          // 8 KB
    __shared__ unsigned segQ[16][128];          // 8 KB
    __shared__ unsigned hn[HSZ];                // 3.84 KB
    __shared__ unsigned long long hT[HSZ];      // 7.68 KB
    __shared__ unsigned long long hQ[HSZ];      // 7.68 KB
    const int c = blockIdx.y, t = threadIdx.x;
    if (t < 16) stg[t] = (t < NBINS) ? tgt[c * NBINS + t] : 0x7FFFFFFF;
    for (int i = t; i < 2048; i += 256) { (&segT[0][0])[i] = 0u; (&segQ[0][0])[i] = 0u; }
    for (int i = t; i < HSZ; i += 256) { hn[i] = 0u; hT[i] = 0ull; hQ[i] = 0ull; }
    __syncthreads();                      // stg ready
    // build bucket->segment table: tbl[k] = #{b : stg[b] <= k} (upper_bound)
    {
        const int k0 = t * 16;
        int j = 0;
        j += (stg[j + 7] <= k0) ? 8 : 0;
        j += (stg[j + 3] <= k0) ? 4 : 0;
        j += (stg[j + 1] <= k0) ? 2 : 0;
        j += (stg[j] <= k0) ? 1 : 0;
        for (int k = k0; k < k0 + 16; ++k) {
            while (j < NBINS && stg[j] <= k) ++j;
            tbl[k] = (unsigned char)j;
        }
    }
    __syncthreads();                      // j-values filled
    if (t < NBINS) tbl[stg[t]] |= 0x80;   // flag target buckets (dupes idempotent)
    __syncthreads();
    const size_t base = (size_t)c * NROWS4;
    const int start = blockIdx.x * CH2;
    const int end = min(NROWS4, start + CH2);
    const int col = t & 127;
    auto proc = [&](float4 v) {
        float val[4] = {v.x, v.y, v.z, v.w};
        unsigned bx[4] = {__float_as_uint(v.x), __float_as_uint(v.y),
                          __float_as_uint(v.z), __float_as_uint(v.w)};
        #pragma unroll
        for (int e = 0; e < 4; ++e) {
            const int k1 = (int)(bx[e] >> 18);
            const unsigned b8 = (unsigned)tbl[k1];
            const int j = (int)(b8 & 15u);
            const unsigned vT = (unsigned)fmaf(val[e], FPS, 0.5f);
            const unsigned vQ = (unsigned)fmaf(val[e] * val[e], FPS, 0.5f);
            atomicAdd(&segT[j][col], vT);            // ds_add_u32, fire-and-forget
            atomicAdd(&segQ[j][col], vQ);
            if (b8 & 0x80u) {             // inside a target bucket: sub-histogram
                int sub = (j - 1) * NSUB + (int)((bx[e] >> 12) & (NSUB - 1));
                atomicAdd(&hn[sub], 1u);
                atomicAdd(&hT[sub], (unsigned long long)vT);   // ds_add_u64
                atomicAdd(&hQ[sub], (unsigned long long)vQ);
            }
        }
    };
    int i = start + t;
    for (; i + 768 < end; i += 1024) {
        float4 w0 = probsT4[base + i];
        float4 w1 = probsT4[base + i + 256];
        float4 w2 = probsT4[base + i + 512];
        float4 w3 = probsT4[base + i + 768];
        proc(w0); proc(w1); proc(w2); proc(w3);
    }
    for (; i < end; i += 256) proc(probsT4[base + i]);
    __syncthreads();
    // flush private sub-hist copy: [blk*NCLS+c][3][960], T/Q converted to float
    int* on = scan2p + ((size_t)(blockIdx.x * NCLS + c) * 3) * HSZ;
    float* oT = (float*)(on + HSZ);
    float* oQ = (float*)(on + 2 * HSZ);
    for (int i2 = t; i2 < HSZ; i2 += 256) {
        on[i2] = (int)hn[i2];
        oT[i2] = (float)((double)hT[i2] * FPI);
        oQ[i2] = (float)((double)hQ[i2] * FPI);
    }
    // reduce seg slots (16 threads per segment, 8 slots each) -> global u64 atomics
    {
        const int j = t >> 4, p = t & 15;
        unsigned long long sT = 0ull, sQ = 0ull;
        #pragma unroll
        for (int i2 = 0; i2 < 8; ++i2) {
            sT += (unsigned long long)segT[j][p * 8 + i2];
            sQ += (unsigned long long)segQ[j][p * 8 + i2];
        }
        #pragma unroll
        for (int o = 8; o; o >>= 1) {
            sT += __shfl_xor(sT, o, 64);
            sQ += __shfl_xor(sQ, o, 64);
        }
        if (p == 0) {
            atomicAdd(&segG[c * 32 + 2 * j], sT);
            atomicAdd(&segG[c * 32 + 2 * j + 1], sQ);
        }
    }
}

// Select sub-bucket (single wave, shfl prefix over 64 subs); cumulative {N,T,Q}
// at the boundary: cumT[b] = (sum_{j<=b} segG_T[j])*2^-24 + sub-prefix
__global__ __launch_bounds__(64) void k_sel2(const int* __restrict__ scan2p,
                                             const int* __restrict__ tgt,
                                             const int* __restrict__ below,
                                             const int* __restrict__ owner,
                                             const unsigned long long* __restrict__ segG,
                                             float* __restrict__ bounds,
                                             int* __restrict__ cumN,
                                             double* __restrict__ cumT,
                                             double* __restrict__ cumQ) {
    const int b = blockIdx.x, c = blockIdx.y, t = threadIdx.x;   // t < 64
    const int ow = owner[c * NBINS + b];
    int nj = 0; float Tj = 0.f, Qj = 0.f;
    for (int k = 0; k < B2; ++k) {
        const int* p = scan2p + ((size_t)(k * NCLS + c) * 3) * HSZ + ow * NSUB + t;
        nj += p[0];
        Tj += ((const float*)p)[HSZ];
        Qj += ((const float*)p)[2 * HSZ];
    }
    const int own = nj;
    #pragma unroll
    for (int d = 1; d < 64; d <<= 1) {
        int nn = __shfl_up(nj, d, 64);
        float TT = __shfl_up(Tj, d, 64);
        float QQ = __shfl_up(Qj, d, 64);
        if (t >= d) { nj += nn; Tj += TT; Qj += QQ; }
    }
    const int bel = below[c * NBINS + b];
    const int lr = rank_target(b) - bel;
    if (lr >= nj - own && lr < nj) {
        unsigned bits = ((unsigned)tgt[c * NBINS + b] << 18) | ((unsigned)t << 12) | 0xFFFu;
        bounds[c * NBINS + b] = __uint_as_float(bits);
        cumN[c * NBINS + b] = bel + nj;
        double A = 0.0, Qd = 0.0;
        for (int jj = 0; jj <= b; ++jj) {
            A  += (double)segG[c * 32 + 2 * jj];
            Qd += (double)segG[c * 32 + 2 * jj + 1];
        }
        cumT[c * NBINS + b] = A * FPI + (double)Tj;
        cumQ[c * NBINS + b] = Qd * FPI + (double)Qj;
    }
}

// Pass 4: label correction from the compact labConf array (coalesced), LDS-staged
// bounds + u64 fixed-point LDS accumulator (int atomics, no FP-CAS), one
// filtered global u64-atomic flush per block
__global__ __launch_bounds__(256) void k_label(const float* __restrict__ labConf,
                                               const int* __restrict__ labels,
                                               const float* __restrict__ bounds,
                                               unsigned long long* __restrict__ accLab) {
    __shared__ float sbd[NCLS * NBINS];                  // 6 KB
    __shared__ unsigned long long sacc[NCLS * NBINS * 2];// 24 KB
    const int t = threadIdx.x;
    for (int i = t; i < NCLS * NBINS; i += 256) sbd[i] = bounds[i];
    for (int i = t; i < NCLS * NBINS * 2; i += 256) sacc[i] = 0ull;
    __syncthreads();
    for (int n = blockIdx.x * 256 + t; n < NROWS; n += gridDim.x * 256) {
        const int c = labels[n];
        const float conf = labConf[n];
        const float* bd = sbd + c * NBINS;
        if (conf > bd[0]) {
            int idx = 0;
            #pragma unroll
            for (int b = 1; b < NBINS; ++b) idx += (conf > bd[b]) ? 1 : 0;
            atomicAdd(&sacc[(c * NBINS + idx) * 2 + 0], 1ull);
            atomicAdd(&sacc[(c * NBINS + idx) * 2 + 1],
                      (unsigned long long)(unsigned)fmaf(conf, FPS, 0.5f));
        }
    }
    __syncthreads();
    for (int i = t; i < NCLS * NBINS * 2; i += 256)
        if (sacc[i]) atomicAdd(&accLab[i], sacc[i]);
}

// Pass 5: closed-form LOO combine in double (totals from segment sums)
__global__ __launch_bounds__(256) void k_final(const unsigned long long* __restrict__ segG,
                                               const int* __restrict__ cumN,
                                               const double* __restrict__ cumT,
                                               const double* __restrict__ cumQ,
                                               const unsigned long long* __restrict__ accLab,
                                               float* __restrict__ out) {
    __shared__ double red[256];
    const int t = threadIdx.x;
    double local = 0.0;
    for (int k = t; k < NCLS * NBINS; k += 256) {
        int c = k / NBINS, b = k - c * NBINS;
        double n, T, Q;
        if (b < NBINS - 1) {
            n = (double)(cumN[k + 1] - cumN[k]);
            T = cumT[k + 1] - cumT[k];
            Q = cumQ[k + 1] - cumQ[k];
        } else {
            unsigned long long uT = 0ull, uQ = 0ull;
            for (int j = 0; j < 16; ++j) {
                uT += segG[c * 32 + 2 * j];
                uQ += segG[c * 32 + 2 * j + 1];
            }
            n = (double)(NROWS - cumN[k]);
            T = (double)uT * FPI - cumT[k];
            Q = (double)uQ * FPI - cumQ[k];
        }
        double S = (double)accLab[k * 2 + 0];
        double T1 = (double)accLab[k * 2 + 1] * FPI;
        if (n > 1.5) {
            double inv = 1.0 / (n - 1.0);
            double a0 = S * inv, a1 = (S - 1.0) * inv;
            local += Q - 2.0 * a0 * T + 2.0 * T1 * inv + (n - S) * a0 * a0 + S * a1 * a1;
        }
    }
    red[t] = local;
    __syncthreads();
    for (int s = 128; s; s >>= 1) {
        if (t < s) red[t] += red[t + s];
        __syncthreads();
    }
    if (t == 0) out[0] = (float)(red[0] / ((double)NROWS * (double)NCLS));
}

extern "C" void kernel_launch(void* const* d_in, const int* in_sizes, int n_in,
                              void* d_out, int out_size, void* d_ws, size_t ws_size,
                              hipStream_t stream) {
    const float* logits = (const float*)d_in[0];
    const int* labels = (const int*)d_in[1];
    float* out = (float*)d_out;
    char* ws = (char*)d_ws;
    size_t off = 0;
    auto alloc = [&](size_t bytes) -> void* {
        off = (off + 255) & ~(size_t)255;
        void* p = ws + off;
        off += bytes;
        return p;
    };
    float* probsT = (float*)alloc((size_t)NCLS * NROWS * 4);               // 200 MB
    // shared region: hist1p (hist1->sel1) then reused as scan2p (scan2->sel2)
    size_t h1bytes = (size_t)B1 * NCLS * 4096 * 4;                         // 22.9 MB
    size_t s2bytes = (size_t)B2 * NCLS * 3 * HSZ * 4;                      // 32.3 MB
    int* hist1p = (int*)alloc(h1bytes > s2bytes ? h1bytes : s2bytes);
    int* scan2p = hist1p;
    float* labConf = (float*)alloc((size_t)NROWS * 4);                     // 2 MB
    // --- zeroed region (contiguous, single small memset) ---
    char* zbase = ws + ((off + 255) & ~(size_t)255);
    unsigned long long* segG   = (unsigned long long*)alloc((size_t)NCLS * 32 * 8);
    unsigned long long* accLab = (unsigned long long*)alloc((size_t)NCLS * NBINS * 2 * 8);
    size_t zlen = (size_t)((ws + off) - zbase);
    // --- written-before-read region ---
    int*    tgt     = (int*)alloc((size_t)NCLS * NBINS * 4);
    int*    below   = (int*)alloc((size_t)NCLS * NBINS * 4);
    int*    owner   = (int*)alloc((size_t)NCLS * NBINS * 4);
    float*  bounds  = (float*)alloc((size_t)NCLS * NBINS * 4);
    int*    cumN    = (int*)alloc((size_t)NCLS * NBINS * 4);
    double* cumT    = (double*)alloc((size_t)NCLS * NBINS * 8);
    double* cumQ    = (double*)alloc((size_t)NCLS * NBINS * 8);
    if (off > ws_size) {
        hipMemsetAsync(d_out, 0xFF, 4, stream);   // NaN sentinel
        return;
    }
    hipMemsetAsync(zbase, 0, zlen, stream);

    k_softmax_t<<<(NROWS + 63) / 64, 256, 0, stream>>>((const float4*)logits, labels,
                                                       probsT, labConf);
    k_hist1<<<dim3(B1, NCLS), 256, 0, stream>>>((const float4*)probsT, hist1p);
    k_sel1<<<NCLS, 256, 0, stream>>>(hist1p, tgt, below, owner);
    k_scan2<<<dim3(B2, NCLS), 256, 0, stream>>>((const float4*)probsT, tgt, scan2p, segG);
    k_sel2<<<dim3(NBINS, NCLS), 64, 0, stream>>>(scan2p, tgt, below, owner, segG,
                                                 bounds, cumN, cumT, cumQ);
    k_label<<<128, 256, 0, stream>>>(labConf, labels, bounds, accLab);
    k_final<<<1, 256, 0, stream>>>(segG, cumN, cumT, cumQ, accLab, out);
}

// Round 8
// 470.313 us; speedup vs baseline: 2.2115x; 1.0026x over previous
//
#include <hip/hip_runtime.h>
#include <stdint.h>

#define NROWS 500000
#define NROWS4 125000
#define NCLS 100
#define NBINS 15
#define NSUB 64          // sub-bucket = 4096 ULP; ~70 elems/sub near mode -> rank err << tolerance
#define B1 14
#define CH1 8929         // ceil(125000/14) float4s per hist1 block
#define B2 28
#define CH2 4465         // ceil(125000/28) float4s per scan2 block
#define HSZ (NBINS * NSUB)   // 960
#define FPS 16777216.0f      // 2^24 fixed-point scale
#define FPI (1.0 / 16777216.0)

__device__ __forceinline__ int rank_target(int b) {
    if (b == 0) return 0;
    const float step = 500000.0f / 15.0f;   // float32-rounded, mimics jnp.linspace
    return (int)floorf((float)b * step);
}

// Pass 1: row softmax of logits [N][C], write transposed probsT [C][N].
// float4 loads, 4-adjacent-lane shfl reduction (exact old summation order ->
// bit-identical probs), 2 syncthreads.  Emits labConf[n] = prob of labeled
// class so k_label never gathers probsT.  (Round-5: issue-side tuning null ->
// this kernel is bound by its ~400MB memory traffic.)
__global__ __launch_bounds__(256) void k_softmax_t(const float4* __restrict__ logits4,
                                                   const int* __restrict__ labels,
                                                   float* __restrict__ probsT,
                                                   float* __restrict__ labConf) {
    __shared__ float tile[64][101];
    __shared__ float inv[64];
    const int row0 = blockIdx.x * 64;
    const int rows = min(64, NROWS - row0);
    const int t = threadIdx.x;
    const float4* lg4 = logits4 + (size_t)row0 * 25;
    const int total4 = rows * 25;
    for (int k = t; k < total4; k += 256) {
        float4 v = lg4[k];
        int r = k / 25, c4 = (k - r * 25) * 4;
        tile[r][c4 + 0] = v.x; tile[r][c4 + 1] = v.y;
        tile[r][c4 + 2] = v.z; tile[r][c4 + 3] = v.w;
    }
    __syncthreads();
    const int r = t >> 2, q = t & 3;   // 4 adjacent lanes per row
    if (r < rows) {
        float m = -1e30f;
        #pragma unroll
        for (int c = 0; c < 25; ++c) m = fmaxf(m, tile[r][q * 25 + c]);
        const int lb = t & ~3;
        float m0 = __shfl(m, lb + 0, 64), m1 = __shfl(m, lb + 1, 64);
        float m2 = __shfl(m, lb + 2, 64), m3 = __shfl(m, lb + 3, 64);
        m = fmaxf(fmaxf(m0, m1), fmaxf(m2, m3));
        float s = 0.f;
        #pragma unroll
        for (int c = 0; c < 25; ++c) {
            float e = __expf(tile[r][q * 25 + c] - m);
            tile[r][q * 25 + c] = e;
            s += e;
        }
        float s0 = __shfl(s, lb + 0, 64), s1 = __shfl(s, lb + 1, 64);
        float s2 = __shfl(s, lb + 2, 64), s3 = __shfl(s, lb + 3, 64);
        if (q == 0) inv[r] = 1.0f / (((s0 + s1) + s2) + s3);
    }
    __syncthreads();
    if (t < rows) {
        const int lab = labels[row0 + t];
        labConf[row0 + t] = tile[t][lab] * inv[t];
    }
    const int shift = (rows == 64) ? 4 : 3;
    const int gq = 1 << shift;
    const int ng = NCLS << shift;
    for (int k = t; k < ng; k += 256) {
        int c = k >> shift, g = k & (gq - 1);
        int rr = g << 2;
        float4 o;
        o.x = tile[rr + 0][c] * inv[rr + 0];
        o.y = tile[rr + 1][c] * inv[rr + 1];
        o.z = tile[rr + 2][c] * inv[rr + 2];
        o.w = tile[rr + 3][c] * inv[rr + 3];
        *(float4*)(probsT + (size_t)c * NROWS + row0 + rr) = o;
    }
}

// Pass 2: per-class L1 histogram (top 12 used float bits), 2 bank-rotated LDS
// copies, non-atomic flush.  Unchanged from round 6 (unroll-null round showed
// it is at its memory/LDS-pipe bound already).
__global__ __launch_bounds__(256) void k_hist1(const float4* __restrict__ probsT4,
                                               int* __restrict__ hist1p) {
    __shared__ int h[2][4096];   // 32 KB
    const int c = blockIdx.y, t = threadIdx.x;
    int4* hz = (int4*)&h[0][0];
    for (int i = t; i < 2048; i += 256) hz[i] = make_int4(0, 0, 0, 0);
    __syncthreads();
    const int copy = t & 1;
    const int rot = copy << 4;
    const size_t base = (size_t)c * NROWS4;
    const int start = blockIdx.x * CH1;
    const int end = min(NROWS4, start + CH1);
    auto proc = [&](float4 v) {
        atomicAdd(&h[copy][((__float_as_uint(v.x) >> 18) + rot) & 4095], 1);
        atomicAdd(&h[copy][((__float_as_uint(v.y) >> 18) + rot) & 4095], 1);
        atomicAdd(&h[copy][((__float_as_uint(v.z) >> 18) + rot) & 4095], 1);
        atomicAdd(&h[copy][((__float_as_uint(v.w) >> 18) + rot) & 4095], 1);
    };
    int i = start + t;
    for (; i + 768 < end; i += 1024) {
        float4 w0 = probsT4[base + i];
        float4 w1 = probsT4[base + i + 256];
        float4 w2 = probsT4[base + i + 512];
        float4 w3 = probsT4[base + i + 768];
        proc(w0); proc(w1); proc(w2); proc(w3);
    }
    for (; i < end; i += 256) proc(probsT4[base + i]);
    __syncthreads();
    int* out = hist1p + ((size_t)blockIdx.x * NCLS + c) * 4096;
    for (int i2 = t; i2 < 4096; i2 += 256)
        out[i2] = h[0][i2] + h[1][(i2 + 16) & 4095];
}

// Select L1 bucket per rank target; parallel prefix (shfl), dedupe via owner[]
// (owner = LAST slot of a duplicate-target group, matching scan2's upper_bound
// table semantics; this pairing passed exact in rounds 1-2 and 4-6)
__global__ __launch_bounds__(256) void k_sel1(const int* __restrict__ hist1p,
                                              int* __restrict__ tgt,
                                              int* __restrict__ below,
                                              int* __restrict__ owner) {
    __shared__ int wsum[4];
    __shared__ int stgt[NBINS];
    __shared__ int sbelow[NBINS];
    const int c = blockIdx.x, t = threadIdx.x;
    int4 acc[4] = {make_int4(0,0,0,0), make_int4(0,0,0,0),
                   make_int4(0,0,0,0), make_int4(0,0,0,0)};
    for (int k = 0; k < B1; ++k) {
        const int4* p = (const int4*)(hist1p + ((size_t)k * NCLS + c) * 4096) + t * 4;
        #pragma unroll
        for (int j = 0; j < 4; ++j) {
            int4 v = p[j];
            acc[j].x += v.x; acc[j].y += v.y; acc[j].z += v.z; acc[j].w += v.w;
        }
    }
    int loc[16];
    #pragma unroll
    for (int j = 0; j < 4; ++j) {
        loc[j * 4 + 0] = acc[j].x; loc[j * 4 + 1] = acc[j].y;
        loc[j * 4 + 2] = acc[j].z; loc[j * 4 + 3] = acc[j].w;
    }
    int s = 0;
    #pragma unroll
    for (int i = 0; i < 16; ++i) s += loc[i];
    // block-wide exclusive prefix of per-thread totals
    const int lane = t & 63, w = t >> 6;
    int incl = s;
    #pragma unroll
    for (int d = 1; d < 64; d <<= 1) {
        int n = __shfl_up(incl, d, 64);
        if (lane >= d) incl += n;
    }
    if (lane == 63) wsum[w] = incl;
    __syncthreads();
    int woff = 0;
    #pragma unroll
    for (int j = 0; j < 4; ++j) if (j < w) woff += wsum[j];
    const int cum0 = woff + incl - s;
    for (int b = 0; b < NBINS; ++b) {
        const int f = rank_target(b);
        int cc = cum0;
        #pragma unroll
        for (int i = 0; i < 16; ++i) {
            if (f >= cc && f < cc + loc[i]) { stgt[b] = t * 16 + i; sbelow[b] = cc; }
            cc += loc[i];
        }
    }
    __syncthreads();
    if (t == 0) {
        int ow = NBINS - 1;
        for (int b = NBINS - 1; b >= 0; --b) {
            if (b == NBINS - 1 || stgt[b] != stgt[b + 1]) ow = b;   // last-of-group
            owner[c * NBINS + b] = ow;
            tgt[c * NBINS + b] = stgt[b];
            below[c * NBINS + b] = sbelow[b];
        }
    }
}

// Pass 3 (round-7 resubmit): segment formulation, INT-ONLY LDS atomics, with
// (a) segT+segQ PACKED into one u64 slot -> single ds_add_u64 per element
//     (overflow-proof: <=144 elems/slot x 2^24 = 2.4e9 < 2^32, so the low
//     (Q) word never carries into the high (T) word), and
// (b) 16-wide gather batching: the unrolled body computes 16 bucket ids,
//     issues 16 independent tbl byte-reads (one lgkmcnt amortized), then
//     emits the atomic phase -- removes the dependent per-element gather
//     latency (~120cy) that serialized the old loop.
// LDS 39.7KB -> 4 blocks/CU unchanged.
__global__ __launch_bounds__(256) void k_scan2(const float4* __restrict__ probsT4,
                                               const int* __restrict__ tgt,
                                               int* __restrict__ scan2p,
                                               unsigned long long* __restrict__ segG) {
    __shared__ int stg[16];
    __shared__ unsigned char tbl[4096];
    __shared__ unsigned long long seg[16][128];  // 16 KB: hi32 = T, lo32 = Q
    __shared__ unsigned hn[HSZ];                 // 3.84 KB
    __shared__ unsigned long long hT[HSZ];       // 7.68 KB
    __shared__ unsigned long long hQ[HSZ];       // 7.68 KB
    const int c = blockIdx.y, t = threadIdx.x;
    if (t < 16) stg[t] = (t < NBINS) ? tgt[c * NBINS + t] : 0x7FFFFFFF;
    for (int i = t; i < 4096; i += 256) ((unsigned*)&seg[0][0])[i] = 0u;
    for (int i = t; i < HSZ; i += 256) { hn[i] = 0u; hT[i] = 0ull; hQ[i] = 0ull; }
    __syncthreads();                      // stg ready
    // build bucket->segment table: tbl[k] = #{b : stg[b] <= k} (upper_bound)
    {
        const int k0 = t * 16;
        int j = 0;
        j += (stg[j + 7] <= k0) ? 8 : 0;
        j += (stg[j + 3] <= k0) ? 4 : 0;
        j += (stg[j + 1] <= k0) ? 2 : 0;
        j += (stg[j] <= k0) ? 1 : 0;
        for (int k = k0; k < k0 + 16; ++k) {
            while (j < NBINS && stg[j] <= k) ++j;
            tbl[k] = (unsigned char)j;
        }
    }
    __syncthreads();                      // j-values filled
    if (t < NBINS) tbl[stg[t]] |= 0x80;   // flag target buckets (dupes idempotent)
    __syncthreads();
    const size_t base = (size_t)c * NROWS4;
    const int start = blockIdx.x * CH2;
    const int end = min(NROWS4, start + CH2);
    const int col = t & 127;
    // emit phase for one element (compile-time index after unroll)
    auto emit = [&](float v, unsigned bx, unsigned b8) {
        const int j = (int)(b8 & 15u);
        const unsigned vT = (unsigned)fmaf(v, FPS, 0.5f);
        const unsigned vQ = (unsigned)fmaf(v * v, FPS, 0.5f);
        atomicAdd(&seg[j][col], ((unsigned long long)vT << 32) | (unsigned long long)vQ);
        if (b8 & 0x80u) {                 // inside a target bucket: sub-histogram
            int sub = (j - 1) * NSUB + (int)((bx >> 12) & (NSUB - 1));
            atomicAdd(&hn[sub], 1u);
            atomicAdd(&hT[sub], (unsigned long long)vT);   // ds_add_u64
            atomicAdd(&hQ[sub], (unsigned long long)vQ);
        }
    };
    int i = start + t;
    for (; i + 768 < end; i += 1024) {
        float4 w0 = probsT4[base + i];
        float4 w1 = probsT4[base + i + 256];
        float4 w2 = probsT4[base + i + 512];
        float4 w3 = probsT4[base + i + 768];
        float va[16] = {w0.x, w0.y, w0.z, w0.w, w1.x, w1.y, w1.z, w1.w,
                        w2.x, w2.y, w2.z, w2.w, w3.x, w3.y, w3.z, w3.w};
        unsigned bxa[16], b8a[16];
        #pragma unroll
        for (int e = 0; e < 16; ++e) bxa[e] = __float_as_uint(va[e]);
        #pragma unroll
        for (int e = 0; e < 16; ++e) b8a[e] = (unsigned)tbl[bxa[e] >> 18];  // gather burst
        #pragma unroll
        for (int e = 0; e < 16; ++e) emit(va[e], bxa[e], b8a[e]);
    }
    for (; i < end; i += 256) {
        float4 v = probsT4[base + i];
        float va[4] = {v.x, v.y, v.z, v.w};
        unsigned bxa[4], b8a[4];
        #pragma unroll
        for (int e = 0; e < 4; ++e) bxa[e] = __float_as_uint(va[e]);
        #pragma unroll
        for (int e = 0; e < 4; ++e) b8a[e] = (unsigned)tbl[bxa[e] >> 18];
        #pragma unroll
        for (int e = 0; e < 4; ++e) emit(va[e], bxa[e], b8a[e]);
    }
    __syncthreads();
    // flush private sub-hist copy: [blk*NCLS+c][3][960], T/Q converted to float
    int* on = scan2p + ((size_t)(blockIdx.x * NCLS + c) * 3) * HSZ;
    float* oT = (float*)(on + HSZ);
    float* oQ = (float*)(on + 2 * HSZ);
    for (int i2 = t; i2 < HSZ; i2 += 256) {
        on[i2] = (int)hn[i2];
        oT[i2] = (float)((double)hT[i2] * FPI);
        oQ[i2] = (float)((double)hQ[i2] * FPI);
    }
    // reduce seg slots (16 threads per segment, 8 slots each) -> global u64 atomics
    {
        const int j = t >> 4, p = t & 15;
        unsigned long long sT = 0ull, sQ = 0ull;
        #pragma unroll
        for (int i2 = 0; i2 < 8; ++i2) {
            unsigned long long wv = seg[j][p * 8 + i2];
            sT += (wv >> 32);
            sQ += (wv & 0xFFFFFFFFull);
        }
        #pragma unroll
        for (int o = 8; o; o >>= 1) {
            sT += __shfl_xor(sT, o, 64);
            sQ += __shfl_xor(sQ, o, 64);
        }
        if (p == 0) {
            atomicAdd(&segG[c * 32 + 2 * j], sT);
            atomicAdd(&segG[c * 32 + 2 * j + 1], sQ);
        }
    }
}

// Select sub-bucket (single wave, shfl prefix over 64 subs); cumulative {N,T,Q}
// at the boundary: cumT[b] = (sum_{j<=b} segG_T[j])*2^-24 + sub-prefix
__global__ __launch_bounds__(64) void k_sel2(const int* __restrict__ scan2p,
                                             const int* __restrict__ tgt,
                                             const int* __restrict__ below,
                                             const int* __restrict__ owner,
                                             const unsigned long long* __restrict__ segG,
                                             float* __restrict__ bounds,
                                             int* __restrict__ cumN,
                                             double* __restrict__ cumT,
                                             double* __restrict__ cumQ) {
    const int b = blockIdx.x, c = blockIdx.y, t = threadIdx.x;   // t < 64
    const int ow = owner[c * NBINS + b];
    int nj = 0; float Tj = 0.f, Qj = 0.f;
    for (int k = 0; k < B2; ++k) {
        const int* p = scan2p + ((size_t)(k * NCLS + c) * 3) * HSZ + ow * NSUB + t;
        nj += p[0];
        Tj += ((const float*)p)[HSZ];
        Qj += ((const float*)p)[2 * HSZ];
    }
    const int own = nj;
    #pragma unroll
    for (int d = 1; d < 64; d <<= 1) {
        int nn = __shfl_up(nj, d, 64);
        float TT = __shfl_up(Tj, d, 64);
        float QQ = __shfl_up(Qj, d, 64);
        if (t >= d) { nj += nn; Tj += TT; Qj += QQ; }
    }
    const int bel = below[c * NBINS + b];
    const int lr = rank_target(b) - bel;
    if (lr >= nj - own && lr < nj) {
        unsigned bits = ((unsigned)tgt[c * NBINS + b] << 18) | ((unsigned)t << 12) | 0xFFFu;
        bounds[c * NBINS + b] = __uint_as_float(bits);
        cumN[c * NBINS + b] = bel + nj;
        double A = 0.0, Qd = 0.0;
        for (int jj = 0; jj <= b; ++jj) {
            A  += (double)segG[c * 32 + 2 * jj];
            Qd += (double)segG[c * 32 + 2 * jj + 1];
        }
        cumT[c * NBINS + b] = A * FPI + (double)Tj;
        cumQ[c * NBINS + b] = Qd * FPI + (double)Qj;
    }
}

// Pass 4: label correction from the compact labConf array (coalesced), LDS-staged
// bounds + u64 fixed-point LDS accumulator (int atomics, no FP-CAS), one
// filtered global u64-atomic flush per block
__global__ __launch_bounds__(256) void k_label(const float* __restrict__ labConf,
                                               const int* __restrict__ labels,
                                               const float* __restrict__ bounds,
                                               unsigned long long* __restrict__ accLab) {
    __shared__ float sbd[NCLS * NBINS];                  // 6 KB
    __shared__ unsigned long long sacc[NCLS * NBINS * 2];// 24 KB
    const int t = threadIdx.x;
    for (int i = t; i < NCLS * NBINS; i += 256) sbd[i] = bounds[i];
    for (int i = t; i < NCLS * NBINS * 2; i += 256) sacc[i] = 0ull;
    __syncthreads();
    for (int n = blockIdx.x * 256 + t; n < NROWS; n += gridDim.x * 256) {
        const int c = labels[n];
        const float conf = labConf[n];
        const float* bd = sbd + c * NBINS;
        if (conf > bd[0]) {
            int idx = 0;
            #pragma unroll
            for (int b = 1; b < NBINS; ++b) idx += (conf > bd[b]) ? 1 : 0;
            atomicAdd(&sacc[(c * NBINS + idx) * 2 + 0], 1ull);
            atomicAdd(&sacc[(c * NBINS + idx) * 2 + 1],
                      (unsigned long long)(unsigned)fmaf(conf, FPS, 0.5f));
        }
    }
    __syncthreads();
    for (int i = t; i < NCLS * NBINS * 2; i += 256)
        if (sacc[i]) atomicAdd(&accLab[i], sacc[i]);
}

// Pass 5: closed-form LOO combine in double (totals from segment sums)
__global__ __launch_bounds__(256) void k_final(const unsigned long long* __restrict__ segG,
                                               const int* __restrict__ cumN,
                                               const double* __restrict__ cumT,
                                               const double* __restrict__ cumQ,
                                               const unsigned long long* __restrict__ accLab,
                                               float* __restrict__ out) {
    __shared__ double red[256];
    const int t = threadIdx.x;
    double local = 0.0;
    for (int k = t; k < NCLS * NBINS; k += 256) {
        int c = k / NBINS, b = k - c * NBINS;
        double n, T, Q;
        if (b < NBINS - 1) {
            n = (double)(cumN[k + 1] - cumN[k]);
            T = cumT[k + 1] - cumT[k];
            Q = cumQ[k + 1] - cumQ[k];
        } else {
            unsigned long long uT = 0ull, uQ = 0ull;
            for (int j = 0; j < 16; ++j) {
                uT += segG[c * 32 + 2 * j];
                uQ += segG[c * 32 + 2 * j + 1];
            }
            n = (double)(NROWS - cumN[k]);
            T = (double)uT * FPI - cumT[k];
            Q = (double)uQ * FPI - cumQ[k];
        }
        double S = (double)accLab[k * 2 + 0];
        double T1 = (double)accLab[k * 2 + 1] * FPI;
        if (n > 1.5) {
            double inv = 1.0 / (n - 1.0);
            double a0 = S * inv, a1 = (S - 1.0) * inv;
            local += Q - 2.0 * a0 * T + 2.0 * T1 * inv + (n - S) * a0 * a0 + S * a1 * a1;
        }
    }
    red[t] = local;
    __syncthreads();
    for (int s = 128; s; s >>= 1) {
        if (t < s) red[t] += red[t + s];
        __syncthreads();
    }
    if (t == 0) out[0] = (float)(red[0] / ((double)NROWS * (double)NCLS));
}

extern "C" void kernel_launch(void* const* d_in, const int* in_sizes, int n_in,
                              void* d_out, int out_size, void* d_ws, size_t ws_size,
                              hipStream_t stream) {
    const float* logits = (const float*)d_in[0];
    const int* labels = (const int*)d_in[1];
    float* out = (float*)d_out;
    char* ws = (char*)d_ws;
    size_t off = 0;
    auto alloc = [&](size_t bytes) -> void* {
        off = (off + 255) & ~(size_t)255;
        void* p = ws + off;
        off += bytes;
        return p;
    };
    float* probsT = (float*)alloc((size_t)NCLS * NROWS * 4);               // 200 MB
    // shared region: hist1p (hist1->sel1) then reused as scan2p (scan2->sel2)
    size_t h1bytes = (size_t)B1 * NCLS * 4096 * 4;                         // 22.9 MB
    size_t s2bytes = (size_t)B2 * NCLS * 3 * HSZ * 4;                      // 32.3 MB
    int* hist1p = (int*)alloc(h1bytes > s2bytes ? h1bytes : s2bytes);
    int* scan2p = hist1p;
    float* labConf = (float*)alloc((size_t)NROWS * 4);                     // 2 MB
    // --- zeroed region (contiguous, single small memset) ---
    char* zbase = ws + ((off + 255) & ~(size_t)255);
    unsigned long long* segG   = (unsigned long long*)alloc((size_t)NCLS * 32 * 8);
    unsigned long long* accLab = (unsigned long long*)alloc((size_t)NCLS * NBINS * 2 * 8);
    size_t zlen = (size_t)((ws + off) - zbase);
    // --- written-before-read region ---
    int*    tgt     = (int*)alloc((size_t)NCLS * NBINS * 4);
    int*    below   = (int*)alloc((size_t)NCLS * NBINS * 4);
    int*    owner   = (int*)alloc((size_t)NCLS * NBINS * 4);
    float*  bounds  = (float*)alloc((size_t)NCLS * NBINS * 4);
    int*    cumN    = (int*)alloc((size_t)NCLS * NBINS * 4);
    double* cumT    = (double*)alloc((size_t)NCLS * NBINS * 8);
    double* cumQ    = (double*)alloc((size_t)NCLS * NBINS * 8);
    if (off > ws_size) {
        hipMemsetAsync(d_out, 0xFF, 4, stream);   // NaN sentinel
        return;
    }
    hipMemsetAsync(zbase, 0, zlen, stream);

    k_softmax_t<<<(NROWS + 63) / 64, 256, 0, stream>>>((const float4*)logits, labels,
                                                       probsT, labConf);
    k_hist1<<<dim3(B1, NCLS), 256, 0, stream>>>((const float4*)probsT, hist1p);
    k_sel1<<<NCLS, 256, 0, stream>>>(hist1p, tgt, below, owner);
    k_scan2<<<dim3(B2, NCLS), 256, 0, stream>>>((const float4*)probsT, tgt, scan2p, segG);
    k_sel2<<<dim3(NBINS, NCLS), 64, 0, stream>>>(scan2p, tgt, below, owner, segG,
                                                 bounds, cumN, cumT, cumQ);
    k_label<<<128, 256, 0, stream>>>(labConf, labels, bounds, accLab);
    k_final<<<1, 256, 0, stream>>>(segG, cumN, cumT, cumQ, accLab, out);
}